// Round 15
// baseline (44784.305 us; speedup 1.0000x reference)
//
#include <hip/hip_runtime.h>
#include <hip/hip_bf16.h>

typedef __attribute__((ext_vector_type(8))) _Float16 half8_t;
typedef __attribute__((ext_vector_type(4))) float f32x4_t;
typedef unsigned long long u64;

#define SH 2056                       // LDS h row stride (elems): 2048 + 8
#define HMOFF (16 * SH)               // plane-2 offset (elems)
#define LDS_BYTES (2 * 16 * SH * 2)   // 131,584 B -> 1 WG/CU, 8 waves = 2/SIMD

__device__ __forceinline__ float sigm(float z) { return 1.0f / (1.0f + __expf(-z)); }
__device__ __forceinline__ float tanh_fast(float z) {
  float e = __expf(2.0f * z);
  return 1.0f - 2.0f / (e + 1.0f);
}

// ---- coherent (cross-XCD) access helpers (SYSTEM scope; fallback path)
__device__ __forceinline__ half8_t ld_h8_coh(const _Float16* p) {
  union { half8_t h; u64 q[2]; } r;
  u64* q = (u64*)p;
  r.q[0] = __hip_atomic_load(q,     __ATOMIC_RELAXED, __HIP_MEMORY_SCOPE_SYSTEM);
  r.q[1] = __hip_atomic_load(q + 1, __ATOMIC_RELAXED, __HIP_MEMORY_SCOPE_SYSTEM);
  return r.h;
}
__device__ __forceinline__ void st_h_coh(_Float16* p, _Float16 v) {
  unsigned short b = __builtin_bit_cast(unsigned short, v);
  __hip_atomic_store((unsigned short*)p, b, __ATOMIC_RELAXED, __HIP_MEMORY_SCOPE_SYSTEM);
}
__device__ __forceinline__ float ld_f_coh(const float* p) {
  return __hip_atomic_load((float*)p, __ATOMIC_RELAXED, __HIP_MEMORY_SCOPE_SYSTEM);
}
__device__ __forceinline__ void st_f_coh(float* p, float v) {
  __hip_atomic_store(p, v, __ATOMIC_RELAXED, __HIP_MEMORY_SCOPE_SYSTEM);
}

// ---- XCD-local load: bypass L1 only (sc0), served by the local L2.
// Valid ONLY when producer and consumer are on the same XCD (fast path).
__device__ __forceinline__ half8_t ld_h8_l2(const _Float16* p) {
  half8_t r;
  asm volatile("global_load_dwordx4 %0, %1, off sc0"
               : "=v"(r) : "v"(p) : "memory");
  return r;
}

// ws layout (bytes) — total 59,940,864 (identical to r10..r14, known-good):
//   W0a  @ 0         : 12582912   (fp16 plane1 = fp16(32*w), [gp][k])
//   W0b  @ 12582912  : 12582912
//   W1a  @ 25165824  : 16777216
//   W1b  @ 41943040  : 16777216
//   vecs @ 58720256  : 98304
//   hch  @ 58818560  : 524288     (h plane1 fp16, [row][h0|h1])
//   hcm  @ 59342848  : 524288     (h plane2 fp16, residual*2048)
//   stats@ 59867136  : 65536      (16 reps x 4 bufs x 256 f32)
//   bars @ 59932672  : 8192       (barriers + xcd slot counters + bad flag)

// permutation (128-col WG groups): gp = colgrp*128 + w*16 + c,
//   gate = c>>2, uo = c&3 ; gcol = gate*1024 + colgrp*32 + w*4 + uo
__global__ void lstm_prep(const float* __restrict__ W0, const float* __restrict__ W1,
                          const float* __restrict__ b0, const float* __restrict__ g0,
                          const float* __restrict__ be0, const float* __restrict__ b1,
                          const float* __restrict__ g1, const float* __restrict__ be1,
                          _Float16* __restrict__ W0a, _Float16* __restrict__ W0b,
                          _Float16* __restrict__ W1a, _Float16* __restrict__ W1b,
                          float* __restrict__ vecs)
{
  int gid = blockIdx.x * 256 + threadIdx.x;
  const int W0N = 192 * 4096;
  const int W1N = 256 * 4096;
  if (gid < W0N) {
    int k8 = gid >> 12, gp = gid & 4095;
    int colgrp = gp >> 7, w = (gp >> 4) & 7, c = gp & 15;
    int gcol = ((c >> 2) << 10) + (colgrp << 5) + (w << 2) + (c & 3);
    half8_t va, vb;
    #pragma unroll
    for (int j = 0; j < 8; ++j) {
      float w32 = W0[(size_t)(k8 * 8 + j) * 4096 + gcol] * 32.0f;
      _Float16 p1 = (_Float16)w32;
      float r = w32 - (float)p1;
      va[j] = p1; vb[j] = (_Float16)(r * 2048.0f);
    }
    *(half8_t*)&W0a[(size_t)gp * 1536 + k8 * 8] = va;
    *(half8_t*)&W0b[(size_t)gp * 1536 + k8 * 8] = vb;
  } else if (gid < W0N + W1N) {
    int g2 = gid - W0N;
    int k8 = g2 >> 12, gp = g2 & 4095;
    int colgrp = gp >> 7, w = (gp >> 4) & 7, c = gp & 15;
    int gcol = ((c >> 2) << 10) + (colgrp << 5) + (w << 2) + (c & 3);
    half8_t va, vb;
    #pragma unroll
    for (int j = 0; j < 8; ++j) {
      float w32 = W1[(size_t)(k8 * 8 + j) * 4096 + gcol] * 32.0f;
      _Float16 p1 = (_Float16)w32;
      float r = w32 - (float)p1;
      va[j] = p1; vb[j] = (_Float16)(r * 2048.0f);
    }
    *(half8_t*)&W1a[(size_t)gp * 2048 + k8 * 8] = va;
    *(half8_t*)&W1b[(size_t)gp * 2048 + k8 * 8] = vb;
  } else if (gid < W0N + W1N + 6 * 4096) {
    int g2 = gid - W0N - W1N;
    int j = g2 >> 12, gp = g2 & 4095;
    int colgrp = gp >> 7, w = (gp >> 4) & 7, c = gp & 15;
    int gcol = ((c >> 2) << 10) + (colgrp << 5) + (w << 2) + (c & 3);
    const float* src = (j == 0) ? b0 : (j == 1) ? g0 : (j == 2) ? be0
                     : (j == 3) ? b1 : (j == 4) ? g1 : be1;
    vecs[j * 4096 + gp] = src[gcol];
  }
}

#define MFMA16(A, B, C) __builtin_amdgcn_mfma_f32_16x16x32_f16(A, B, C, 0, 0, 0)

// ---- one-time full-grid barrier (r7-proven 8x32 structure), used at startup
__device__ __forceinline__ void gridbar256(unsigned* bars, int wgid, int tid, unsigned ep) {
  __syncthreads();
  if (tid == 0) {
    const int q = ep & 1;
    unsigned old = __hip_atomic_fetch_add(&bars[(q * 8 + (wgid & 7)) * 32], 1u,
                                          __ATOMIC_RELAXED, __HIP_MEMORY_SCOPE_AGENT);
    if (old == 31u) {
      unsigned mo = __hip_atomic_fetch_add(&bars[512 + q * 32], 1u,
                                           __ATOMIC_RELAXED, __HIP_MEMORY_SCOPE_AGENT);
      if (mo == 7u) {
        #pragma unroll
        for (int g = 0; g < 8; ++g)
          __hip_atomic_store(&bars[(q * 8 + g) * 32], 0u, __ATOMIC_RELAXED, __HIP_MEMORY_SCOPE_SYSTEM);
        __hip_atomic_store(&bars[512 + q * 32], 0u, __ATOMIC_RELAXED, __HIP_MEMORY_SCOPE_SYSTEM);
        __hip_atomic_store(&bars[576], ep, __ATOMIC_RELEASE, __HIP_MEMORY_SCOPE_SYSTEM);
      }
    }
    while (__hip_atomic_load(&bars[576], __ATOMIC_RELAXED, __HIP_MEMORY_SCOPE_SYSTEM) < ep) {}
  }
  __syncthreads();
}

// ---- GROUP-LOCAL barrier: 32 arrivals (one mtile group)
__device__ __forceinline__ void groupbar(unsigned* bars, int grp, int tid, unsigned ep) {
  __syncthreads();
  if (tid == 0) {
    const int q = ep & 1;
    unsigned old = __hip_atomic_fetch_add(&bars[(grp * 2 + q) * 32], 1u,
                                          __ATOMIC_RELAXED, __HIP_MEMORY_SCOPE_AGENT);
    if (old == 31u) {
      __hip_atomic_store(&bars[(grp * 2 + q) * 32], 0u, __ATOMIC_RELAXED, __HIP_MEMORY_SCOPE_SYSTEM);
      __hip_atomic_store(&bars[1024 + grp * 32], ep, __ATOMIC_RELEASE, __HIP_MEMORY_SCOPE_SYSTEM);
    }
    while (__hip_atomic_load(&bars[1024 + grp * 32], __ATOMIC_RELAXED, __HIP_MEMORY_SCOPE_SYSTEM) < ep) {}
  }
  __syncthreads();
}

// 256 WGs x 512 thr. Groups SELF-ORGANIZE onto XCDs at runtime (getreg XCC_ID +
// slot atomics, validated by a one-time grid barrier). Fast path: all h exchange
// is XCD-local -> plain stores + sc0 loads served by the local L2 (no SYSTEM
// traffic). Any validation failure -> exact r14 fallback (wgid mapping + SYSTEM).
__global__ void __launch_bounds__(512, 2) lstm_seq(
    const float* __restrict__ x,
    const _Float16* __restrict__ W0ap,
    const _Float16* __restrict__ W0bp,
    const _Float16* __restrict__ W1ap,
    const _Float16* __restrict__ W1bp,
    const float* __restrict__ vecs,
    _Float16* __restrict__ hch,
    _Float16* __restrict__ hcm,
    float* __restrict__ stats,
    unsigned* __restrict__ bars,
    const float* __restrict__ fcW,
    const float* __restrict__ fcb,
    float* __restrict__ out)
{
  extern __shared__ _Float16 hS[];    // [2 planes][16 rows][SH]
  __shared__ unsigned sMeta[2];       // [slot, xcc]
  const int tid = threadIdx.x;
  const int wgid = blockIdx.x;
  const int wid = tid >> 6;            // 0..7 = 16-col tile
  const int lane = tid & 63;
  const int c16 = lane & 15;
  const int klo = lane >> 4;

  // ---- self-organize groups by physical XCD ----
  if (tid == 0) {
    unsigned xcc = __builtin_amdgcn_s_getreg((3 << 11) | 20) & 15u;  // HW_REG_XCC_ID, 4 bits
    unsigned slot = __hip_atomic_fetch_add(&bars[1536 + (xcc & 7u)], 1u,
                                           __ATOMIC_RELAXED, __HIP_MEMORY_SCOPE_AGENT);
    if (slot >= 32u || xcc > 7u)
      __hip_atomic_fetch_or(&bars[1544], 1u, __ATOMIC_ACQ_REL, __HIP_MEMORY_SCOPE_SYSTEM);
    sMeta[0] = slot; sMeta[1] = xcc & 7u;
  }
  unsigned ep = 1;
  gridbar256(bars, wgid, tid, ep);    // all assignments + bad-flag visible after
  const unsigned bad = __hip_atomic_load(&bars[1544], __ATOMIC_ACQUIRE, __HIP_MEMORY_SCOPE_SYSTEM);
  const bool fast = (bad == 0u);
  const int mtile  = fast ? (int)sMeta[1] : (wgid >> 5);   // 0..7 = group
  const int colgrp = fast ? (int)sMeta[0] : (wgid & 31);   // 0..31
  const int rowbase = mtile * 16;

  const int gp = colgrp * 128 + wid * 16 + c16;
  const float b0v  = vecs[gp];
  const float g0v  = vecs[4096 + gp];
  const float be0v = vecs[8192 + gp];
  const float b1v  = vecs[12288 + gp];
  const float g1v  = vecs[16384 + gp];
  const float be1v = vecs[20480 + gp];

  const int arow = rowbase + c16;
  const float* xbase = x + (size_t)arow * 512 * 512; // x[row][t][d]
  const _Float16* w0a = W0ap + (size_t)gp * 1536;
  const _Float16* w0b = W0bp + (size_t)gp * 1536;
  const _Float16* w1a = W1ap + (size_t)gp * 2048;
  const _Float16* w1b = W1bp + (size_t)gp * 2048;
  const int repbase = (colgrp & 15) << 2;            // rep*4 for stats writes
  const int cbase = colgrp * 32 + wid * 4;           // h-unit base for this wave

  float c0s[4] = {0,0,0,0};
  float c1s[4] = {0,0,0,0};
  half8_t stg[16];                    // in-flight stage registers

#define STAGE_ADDR(J, SRCP)                                                   \
      int linear = tid + 512 * (J);                                           \
      int plane = linear >> 12;                                               \
      int rem = linear & 4095;                                                \
      int row = rem >> 8;                                                     \
      int ck  = rem & 255;                                                    \
      const _Float16* SRCP = (plane ? hcm : hch)                              \
                           + (size_t)(rowbase + row) * 2048 + ck * 8;

// fast: sc0 loads (local-L2-served), bulk waitcnt, LDS write, sync
#define STAGE_FAST() {                                                        \
    _Pragma("unroll")                                                         \
    for (int j = 0; j < 16; ++j) { STAGE_ADDR(j, srcp) stg[j] = ld_h8_l2(srcp); } \
    asm volatile("s_waitcnt vmcnt(0)" ::: "memory");                          \
    __builtin_amdgcn_sched_barrier(0);                                        \
    _Pragma("unroll")                                                         \
    for (int j = 0; j < 16; ++j) {                                            \
      int linear = tid + 512 * j;                                             \
      int plane = linear >> 12;                                               \
      int rem = linear & 4095;                                                \
      int row = rem >> 8;                                                     \
      int ck  = rem & 255;                                                    \
      *(half8_t*)&hS[plane * HMOFF + row * SH + ck * 8] = stg[j];             \
    }                                                                         \
    __syncthreads(); }

// fallback: r14's async split (SYSTEM loads, compiler-tracked)
#define STAGE_ISSUE() {                                                       \
    _Pragma("unroll")                                                         \
    for (int j = 0; j < 16; ++j) { STAGE_ADDR(j, srcp) stg[j] = ld_h8_coh(srcp); } }

#define STAGE_COMMIT() {                                                      \
    _Pragma("unroll")                                                         \
    for (int j = 0; j < 16; ++j) {                                            \
      int linear = tid + 512 * j;                                             \
      int plane = linear >> 12;                                               \
      int rem = linear & 4095;                                                \
      int row = rem >> 8;                                                     \
      int ck  = rem & 255;                                                    \
      *(half8_t*)&hS[plane * HMOFF + row * SH + ck * 8] = stg[j];             \
    }                                                                         \
    __syncthreads(); }

#define SPLIT2(E, J) { float e_ = (E); _Float16 h1_ = (_Float16)e_;           \
  float r_ = e_ - (float)h1_; ah[J] = h1_; am[J] = (_Float16)(r_ * 2048.0f); }

#define PROD3(HA, MA) \
  HA = MFMA16(ah, bh0, HA);                                                   \
  MA = MFMA16(ah, bm0, MA);                                                   \
  MA = MFMA16(am, bh0, MA);

#define X_BODY(KB, HA, MA) {                                                  \
      float4 xu = *(const float4*)(xp + (KB) * 32);                           \
      float4 xw = *(const float4*)(xp + (KB) * 32 + 4);                       \
      half8_t ah, am;                                                         \
      SPLIT2(xu.x, 0) SPLIT2(xu.y, 1) SPLIT2(xu.z, 2) SPLIT2(xu.w, 3)         \
      SPLIT2(xw.x, 4) SPLIT2(xw.y, 5) SPLIT2(xw.z, 6) SPLIT2(xw.w, 7)         \
      half8_t bh0 = *(const half8_t*)&w0a[(KB) * 32 + klo * 8];               \
      half8_t bm0 = *(const half8_t*)&w0b[(KB) * 32 + klo * 8];               \
      PROD3(HA, MA) }

#define H0_BODY(KB, HA, MA) {                                                 \
      half8_t ah = *(const half8_t*)&hS[c16 * SH + (KB) * 32 + klo * 8];      \
      half8_t am = *(const half8_t*)&hS[HMOFF + c16 * SH + (KB) * 32 + klo * 8]; \
      half8_t bh0 = *(const half8_t*)&w0a[512 + (KB) * 32 + klo * 8];         \
      half8_t bm0 = *(const half8_t*)&w0b[512 + (KB) * 32 + klo * 8];         \
      PROD3(HA, MA) }

#define H1_BODY(KB, HA, MA) {                                                 \
      half8_t ah = *(const half8_t*)&hS[c16 * SH + (KB) * 32 + klo * 8];      \
      half8_t am = *(const half8_t*)&hS[HMOFF + c16 * SH + (KB) * 32 + klo * 8]; \
      half8_t bh0 = *(const half8_t*)&w1a[(KB) * 32 + klo * 8];               \
      half8_t bm0 = *(const half8_t*)&w1b[(KB) * 32 + klo * 8];               \
      PROD3(HA, MA) }

#define STAT_ADD(V, BUF) {                                                    \
    _Pragma("unroll")                                                         \
    for (int r = 0; r < 4; ++r) {                                             \
      float s = V[r];                                                         \
      float q = V[r]*V[r];                                                    \
      _Pragma("unroll")                                                       \
      for (int m = 1; m <= 8; m <<= 1) { s += __shfl_xor(s, m); q += __shfl_xor(q, m); } \
      if (c16 == 0) {                                                         \
        int row = rowbase + klo * 4 + r;                                      \
        atomicAdd(&stats[(repbase + (BUF)) * 256 + row * 2 + 0], s);          \
        atomicAdd(&stats[(repbase + (BUF)) * 256 + row * 2 + 1], q);          \
      }                                                                       \
    } }

// LN + LSTM cell. Stats stay SYSTEM (tiny traffic); h writes switch on `fast`.
#define CELL(V, BUF, CS, GC, BEC, HB) {                                       \
    _Pragma("unroll")                                                         \
    for (int r = 0; r < 4; ++r) {                                             \
      int row = rowbase + klo * 4 + r;                                        \
      const float* sp = stats + ((c16 << 2) + (BUF)) * 256 + row * 2;         \
      float s_ = ld_f_coh(sp), q_ = ld_f_coh(sp + 1);                         \
      _Pragma("unroll")                                                       \
      for (int m = 1; m <= 8; m <<= 1) { s_ += __shfl_xor(s_, m); q_ += __shfl_xor(q_, m); } \
      float mean = s_ * (1.0f / 4096.0f);                                     \
      float msq  = q_ * (1.0f / 4096.0f);                                     \
      float rstd = rsqrtf(msq - mean * mean + 1e-5f);                         \
      float gh = (V[r] - mean) * rstd * GC + BEC;                             \
      float fg = __shfl_down(gh, 4);                                          \
      float gg = __shfl_down(gh, 8);                                          \
      float og = __shfl_down(gh, 12);                                         \
      if (c16 < 4) {                                                          \
        float iv = sigm(gh), fv = sigm(fg), zv = tanh_fast(gg), ov = sigm(og); \
        float cc = fv * CS[r] + iv * zv;                                      \
        CS[r] = cc;                                                           \
        float hv = ov * tanh_fast(cc);                                        \
        int idx = row * 2048 + (HB) + cbase + c16;                            \
        _Float16 h1v = (_Float16)hv;                                          \
        _Float16 h2v = (_Float16)((hv - (float)h1v) * 2048.0f);               \
        if (fast) { hch[idx] = h1v; hcm[idx] = h2v; }                         \
        else { st_h_coh(&hch[idx], h1v); st_h_coh(&hcm[idx], h2v); }          \
      }                                                                       \
    } }

  f32x4_t ahe, aho, ame, amo;     // layer-0 accumulators
  f32x4_t dhe, dho, dme, dmo;     // layer-1 accumulators
  f32x4_t a0, d0;

#define A0_X(TT) {                                                            \
    ahe = {0,0,0,0}; aho = {0,0,0,0}; ame = {0,0,0,0}; amo = {0,0,0,0};       \
    const float* xp = xbase + (size_t)(TT) * 512 + klo * 8;                   \
    _Pragma("unroll 2")                                                       \
    for (int kb = 0; kb < 16; kb += 2) {                                      \
      X_BODY(kb,     ahe, ame);                                               \
      X_BODY(kb + 1, aho, amo);                                               \
    } }

#define A0_COMBINE() {                                                        \
    a0 = (ahe + aho) * 0.03125f + (ame + amo) * (1.0f / 65536.0f);            \
    _Pragma("unroll")                                                         \
    for (int r_ = 0; r_ < 4; ++r_) a0[r_] += b0v; }

  // ---------------- prologue: A0[0] (h planes are zeroed) ----------------
  if (fast) { STAGE_FAST(); }
  else { STAGE_ISSUE(); STAGE_COMMIT(); }
  A0_X(0);
  #pragma unroll 2
  for (int kb = 0; kb < 32; kb += 2) {
    H0_BODY(kb,     ahe, ame);
    H0_BODY(kb + 1, aho, amo);
  }
  A0_COMBINE();
  STAT_ADD(a0, 0);
  groupbar(bars, mtile, tid, ++ep);
  CELL(a0, 0, c0s, g0v, be0v, 0);
  groupbar(bars, mtile, tid, ++ep);

  // ---------------- main loop ----------------
  for (int t = 0; t < 512; ++t) {
    const int par = t & 1;
    const int npar = 1 - par;

    // ===== alpha[t]: stage {h0[t], h1[t-1]}; then FUSED H1 + A0_H0 =====
    if (fast) {
      STAGE_FAST();                // L2-local, ~fast; no overlap needed
      if (t < 511) A0_X(t + 1);
    } else {
      STAGE_ISSUE();               // SYSTEM loads in flight...
      if (t < 511) A0_X(t + 1);    // ...hidden under h-independent X-part
      STAGE_COMMIT();
    }

    dhe = {0,0,0,0}; dho = {0,0,0,0}; dme = {0,0,0,0}; dmo = {0,0,0,0};
    if (t < 511) {
      #pragma unroll 2
      for (int i = 0; i < 32; i += 2) {
        H1_BODY(2*i,     dhe, dme);
        H1_BODY(2*i+1,   dho, dmo);
        H0_BODY(i,       ahe, ame);
        H1_BODY(2*i+2,   dhe, dme);
        H1_BODY(2*i+3,   dho, dmo);
        H0_BODY(i+1,     aho, amo);
      }
    } else {
      #pragma unroll 2
      for (int kb = 0; kb < 64; kb += 2) {
        H1_BODY(kb,     dhe, dme);
        H1_BODY(kb + 1, dho, dmo);
      }
    }
    d0 = (dhe + dho) * 0.03125f + (dme + dmo) * (1.0f / 65536.0f);
    #pragma unroll
    for (int r = 0; r < 4; ++r) d0[r] += b1v;
    STAT_ADD(d0, 2 + par);

    if (t < 511) {
      A0_COMBINE();
      STAT_ADD(a0, npar);
    }

    // group-local stats zeroing
    if (colgrp < 16 && tid < 64) {
      int bufsel = ((tid >> 5) == 0) ? (2 + npar) : par;
      st_f_coh(&stats[((colgrp << 2) + bufsel) * 256 + mtile * 32 + (tid & 31)], 0.0f);
    }

    groupbar(bars, mtile, tid, ++ep);

    // ===== beta[t]: B1[t] (+ B0[t+1]) =====
    CELL(d0, 2 + par, c1s, g1v, be1v, 1024);
    if (t < 511) {
      CELL(a0, npar, c0s, g0v, be0v, 0);
    }
    groupbar(bars, mtile, tid, ++ep);
  }

  // ---------------- final fc (group-local): rows of this mtile ----------
  {
    if (tid < 256) {
      int b = rowbase + (tid >> 4);
      int o = colgrp * 16 + (tid & 15);
      const _Float16* p1 = hch + (size_t)b * 2048 + 1024;
      const _Float16* p2 = hcm + (size_t)b * 2048 + 1024;
      float s = fcb[o];
      #pragma unroll 4
      for (int k = 0; k < 1024; k += 4) {
        union { u64 q; _Float16 h[4]; } ua, um;
        ua.q = __hip_atomic_load((u64*)(p1 + k), __ATOMIC_RELAXED, __HIP_MEMORY_SCOPE_SYSTEM);
        um.q = __hip_atomic_load((u64*)(p2 + k), __ATOMIC_RELAXED, __HIP_MEMORY_SCOPE_SYSTEM);
        #pragma unroll
        for (int i = 0; i < 4; ++i) {
          float h = (float)ua.h[i] + (float)um.h[i] * (1.0f / 2048.0f);
          s = fmaf(h, fcW[(k + i) * 512 + o], s);
        }
      }
      out[b * 512 + o] = s;
    }
  }
}

extern "C" void kernel_launch(void* const* d_in, const int* in_sizes, int n_in,
                              void* d_out, int out_size, void* d_ws, size_t ws_size,
                              hipStream_t stream) {
  const float* x   = (const float*)d_in[0];
  const float* W0  = (const float*)d_in[1];
  const float* b0  = (const float*)d_in[2];
  const float* g0  = (const float*)d_in[3];
  const float* be0 = (const float*)d_in[4];
  const float* W1  = (const float*)d_in[5];
  const float* b1  = (const float*)d_in[6];
  const float* g1  = (const float*)d_in[7];
  const float* be1 = (const float*)d_in[8];
  const float* fcW = (const float*)d_in[9];
  const float* fcb = (const float*)d_in[10];
  float* out = (float*)d_out;

  char* ws = (char*)d_ws;
  _Float16* W0a  = (_Float16*)(ws);
  _Float16* W0b  = (_Float16*)(ws + 12582912);
  _Float16* W1a  = (_Float16*)(ws + 25165824);
  _Float16* W1b  = (_Float16*)(ws + 41943040);
  float* vecs    = (float*)(ws + 58720256);
  _Float16* hch  = (_Float16*)(ws + 58818560);
  _Float16* hcm  = (_Float16*)(ws + 59342848);
  float* stats   = (float*)(ws + 59867136);
  unsigned* bars = (unsigned*)(ws + 59932672);

  // re-zero h planes + stats + barrier/slot state every call (graph replays)
  hipMemsetAsync(hch, 0, 524288 + 524288 + 65536 + 8192, stream);
  lstm_prep<<<7264, 256, 0, stream>>>(W0, W1, b0, g0, be0, b1, g1, be1,
                                      W0a, W0b, W1a, W1b, vecs);

  hipFuncSetAttribute((const void*)lstm_seq,
                      hipFuncAttributeMaxDynamicSharedMemorySize, LDS_BYTES);
  void* args[] = { (void*)&x, (void*)&W0a, (void*)&W0b, (void*)&W1a, (void*)&W1b,
                   (void*)&vecs, (void*)&hch, (void*)&hcm,
                   (void*)&stats, (void*)&bars,
                   (void*)&fcW, (void*)&fcb, (void*)&out };
  hipError_t lerr = hipLaunchCooperativeKernel((const void*)lstm_seq,
                                               dim3(256), dim3(512),
                                               args, LDS_BYTES, stream);
  if (lerr != hipSuccess) {
    (void)hipGetLastError();
    lstm_seq<<<dim3(256), dim3(512), LDS_BYTES, stream>>>(
        x, W0a, W0b, W1a, W1b, vecs, hch, hcm, stats, bars, fcW, fcb, out);
  }
}

// Round 16
// 41710.065 us; speedup vs baseline: 1.0737x; 1.0737x over previous
//
#include <hip/hip_runtime.h>
#include <hip/hip_bf16.h>

typedef __attribute__((ext_vector_type(8))) _Float16 half8_t;
typedef __attribute__((ext_vector_type(4))) float f32x4_t;
typedef unsigned long long u64;

#define SH 2056                       // LDS h row stride (elems): 2048 + 8
#define HMOFF (16 * SH)               // plane-2 offset (elems)
#define LDS_BYTES (2 * 16 * SH * 2)   // 131,584 B -> 1 WG/CU, 8 waves = 2/SIMD

#define WS_BASE 59940864u             // r10..r14 known-good layout size
#define SCR_BYTES 8388608u            // 8 MiB: per-(XCD,mtile) h bounce buffers

__device__ __forceinline__ float sigm(float z) { return 1.0f / (1.0f + __expf(-z)); }
__device__ __forceinline__ float tanh_fast(float z) {
  float e = __expf(2.0f * z);
  return 1.0f - 2.0f / (e + 1.0f);
}

// ---- coherent (cross-XCD) access helpers (SYSTEM scope)
__device__ __forceinline__ half8_t ld_h8_coh(const _Float16* p) {
  union { half8_t h; u64 q[2]; } r;
  u64* q = (u64*)p;
  r.q[0] = __hip_atomic_load(q,     __ATOMIC_RELAXED, __HIP_MEMORY_SCOPE_SYSTEM);
  r.q[1] = __hip_atomic_load(q + 1, __ATOMIC_RELAXED, __HIP_MEMORY_SCOPE_SYSTEM);
  return r.h;
}
__device__ __forceinline__ void st_h_coh(_Float16* p, _Float16 v) {
  unsigned short b = __builtin_bit_cast(unsigned short, v);
  __hip_atomic_store((unsigned short*)p, b, __ATOMIC_RELAXED, __HIP_MEMORY_SCOPE_SYSTEM);
}
__device__ __forceinline__ float ld_f_coh(const float* p) {
  return __hip_atomic_load((float*)p, __ATOMIC_RELAXED, __HIP_MEMORY_SCOPE_SYSTEM);
}
__device__ __forceinline__ void st_f_coh(float* p, float v) {
  __hip_atomic_store(p, v, __ATOMIC_RELAXED, __HIP_MEMORY_SCOPE_SYSTEM);
}

// ---- XCD-local load: bypass L1 only (sc0), served by the local L2 (r15-proven)
__device__ __forceinline__ half8_t ld_h8_l2(const _Float16* p) {
  half8_t r;
  asm volatile("global_load_dwordx4 %0, %1, off sc0"
               : "=v"(r) : "v"(p) : "memory");
  return r;
}

// ws layout (bytes):
//   W0a  @ 0         : 12582912   (fp16 plane1 = fp16(32*w), [gp][k])
//   W0b  @ 12582912  : 12582912
//   W1a  @ 25165824  : 16777216
//   W1b  @ 41943040  : 16777216
//   vecs @ 58720256  : 98304
//   hch  @ 58818560  : 524288     (h truth plane1 fp16, [row][h0|h1])
//   hcm  @ 59342848  : 524288     (h truth plane2 fp16, residual*2048)
//   stats@ 59867136  : 65536      (16 reps x 4 bufs x 256 f32)
//   bars @ 59932672  : 8192
//   scr  @ 59940864  : 8388608    (OPTIONAL, only if ws_size allows:
//                                  [xcd*8+mtile][2 planes][16 rows][2048] fp16)

// permutation (128-col WG groups): gp = colgrp*128 + w*16 + c,
//   gate = c>>2, uo = c&3 ; gcol = gate*1024 + colgrp*32 + w*4 + uo
__global__ void lstm_prep(const float* __restrict__ W0, const float* __restrict__ W1,
                          const float* __restrict__ b0, const float* __restrict__ g0,
                          const float* __restrict__ be0, const float* __restrict__ b1,
                          const float* __restrict__ g1, const float* __restrict__ be1,
                          _Float16* __restrict__ W0a, _Float16* __restrict__ W0b,
                          _Float16* __restrict__ W1a, _Float16* __restrict__ W1b,
                          float* __restrict__ vecs)
{
  int gid = blockIdx.x * 256 + threadIdx.x;
  const int W0N = 192 * 4096;
  const int W1N = 256 * 4096;
  if (gid < W0N) {
    int k8 = gid >> 12, gp = gid & 4095;
    int colgrp = gp >> 7, w = (gp >> 4) & 7, c = gp & 15;
    int gcol = ((c >> 2) << 10) + (colgrp << 5) + (w << 2) + (c & 3);
    half8_t va, vb;
    #pragma unroll
    for (int j = 0; j < 8; ++j) {
      float w32 = W0[(size_t)(k8 * 8 + j) * 4096 + gcol] * 32.0f;
      _Float16 p1 = (_Float16)w32;
      float r = w32 - (float)p1;
      va[j] = p1; vb[j] = (_Float16)(r * 2048.0f);
    }
    *(half8_t*)&W0a[(size_t)gp * 1536 + k8 * 8] = va;
    *(half8_t*)&W0b[(size_t)gp * 1536 + k8 * 8] = vb;
  } else if (gid < W0N + W1N) {
    int g2 = gid - W0N;
    int k8 = g2 >> 12, gp = g2 & 4095;
    int colgrp = gp >> 7, w = (gp >> 4) & 7, c = gp & 15;
    int gcol = ((c >> 2) << 10) + (colgrp << 5) + (w << 2) + (c & 3);
    half8_t va, vb;
    #pragma unroll
    for (int j = 0; j < 8; ++j) {
      float w32 = W1[(size_t)(k8 * 8 + j) * 4096 + gcol] * 32.0f;
      _Float16 p1 = (_Float16)w32;
      float r = w32 - (float)p1;
      va[j] = p1; vb[j] = (_Float16)(r * 2048.0f);
    }
    *(half8_t*)&W1a[(size_t)gp * 2048 + k8 * 8] = va;
    *(half8_t*)&W1b[(size_t)gp * 2048 + k8 * 8] = vb;
  } else if (gid < W0N + W1N + 6 * 4096) {
    int g2 = gid - W0N - W1N;
    int j = g2 >> 12, gp = g2 & 4095;
    int colgrp = gp >> 7, w = (gp >> 4) & 7, c = gp & 15;
    int gcol = ((c >> 2) << 10) + (colgrp << 5) + (w << 2) + (c & 3);
    const float* src = (j == 0) ? b0 : (j == 1) ? g0 : (j == 2) ? be0
                     : (j == 3) ? b1 : (j == 4) ? g1 : be1;
    vecs[j * 4096 + gp] = src[gcol];
  }
}

#define MFMA16(A, B, C) __builtin_amdgcn_mfma_f32_16x16x32_f16(A, B, C, 0, 0, 0)

// ---- one-time full-grid barrier (r7-proven), startup only (resets its counters)
__device__ __forceinline__ void gridbar256(unsigned* bars, int wgid, int tid, unsigned ep) {
  __syncthreads();
  if (tid == 0) {
    const int q = ep & 1;
    unsigned old = __hip_atomic_fetch_add(&bars[(q * 8 + (wgid & 7)) * 32], 1u,
                                          __ATOMIC_RELAXED, __HIP_MEMORY_SCOPE_AGENT);
    if (old == 31u) {
      unsigned mo = __hip_atomic_fetch_add(&bars[512 + q * 32], 1u,
                                           __ATOMIC_RELAXED, __HIP_MEMORY_SCOPE_AGENT);
      if (mo == 7u) {
        #pragma unroll
        for (int g = 0; g < 8; ++g)
          __hip_atomic_store(&bars[(q * 8 + g) * 32], 0u, __ATOMIC_RELAXED, __HIP_MEMORY_SCOPE_SYSTEM);
        __hip_atomic_store(&bars[512 + q * 32], 0u, __ATOMIC_RELAXED, __HIP_MEMORY_SCOPE_SYSTEM);
        __hip_atomic_store(&bars[576], ep, __ATOMIC_RELEASE, __HIP_MEMORY_SCOPE_SYSTEM);
      }
    }
    while (__hip_atomic_load(&bars[576], __ATOMIC_RELAXED, __HIP_MEMORY_SCOPE_SYSTEM) < ep) {}
  }
  __syncthreads();
}

// ---- GROUP-LOCAL barrier: 32 arrivals (one mtile group; spans XCDs)
__device__ __forceinline__ void groupbar(unsigned* bars, int grp, int tid, unsigned ep) {
  __syncthreads();
  if (tid == 0) {
    const int q = ep & 1;
    unsigned old = __hip_atomic_fetch_add(&bars[(grp * 2 + q) * 32], 1u,
                                          __ATOMIC_RELAXED, __HIP_MEMORY_SCOPE_AGENT);
    if (old == 31u) {
      __hip_atomic_store(&bars[(grp * 2 + q) * 32], 0u, __ATOMIC_RELAXED, __HIP_MEMORY_SCOPE_SYSTEM);
      __hip_atomic_store(&bars[1024 + grp * 32], ep, __ATOMIC_RELEASE, __HIP_MEMORY_SCOPE_SYSTEM);
    }
    while (__hip_atomic_load(&bars[1024 + grp * 32], __ATOMIC_RELAXED, __HIP_MEMORY_SCOPE_SYSTEM) < ep) {}
  }
  __syncthreads();
}

// ---- SIBLING barrier: 4 arrivals (same XCD, same mtile). xm = xcd*8+mtile.
__device__ __forceinline__ void sibbar(unsigned* bars, int xm, int tid, unsigned ep) {
  __syncthreads();
  if (tid == 0) {
    const int q = ep & 1;
    unsigned old = __hip_atomic_fetch_add(&bars[1600 + xm * 2 + q], 1u,
                                          __ATOMIC_RELAXED, __HIP_MEMORY_SCOPE_AGENT);
    if (old == 3u) {
      __hip_atomic_store(&bars[1600 + xm * 2 + q], 0u, __ATOMIC_RELAXED, __HIP_MEMORY_SCOPE_AGENT);
      __hip_atomic_store(&bars[1792 + xm], ep, __ATOMIC_RELEASE, __HIP_MEMORY_SCOPE_AGENT);
    }
    while (__hip_atomic_load(&bars[1792 + xm], __ATOMIC_RELAXED, __HIP_MEMORY_SCOPE_AGENT) < ep) {}
  }
  __syncthreads();
}

// 256 WGs x 512 thr. Self-org onto XCDs reproducing r14's WEIGHT-LOCAL layout
// (mtile = slot>>2, colgrp = (slot&3)*8 + xcd). If mode==1 and placement
// validates: 4 same-(XCD,mtile) siblings cooperatively stage h — each SYSTEM-
// reads 1/4, bounces via XCD-local scratch (plain store -> own L2, sc0 read).
// SYSTEM h-read traffic drops 32 -> 8 MB/step. Otherwise: exact r14 path.
__global__ void __launch_bounds__(512, 2) lstm_seq(
    const float* __restrict__ x,
    const _Float16* __restrict__ W0ap,
    const _Float16* __restrict__ W0bp,
    const _Float16* __restrict__ W1ap,
    const _Float16* __restrict__ W1bp,
    const float* __restrict__ vecs,
    _Float16* __restrict__ hch,
    _Float16* __restrict__ hcm,
    float* __restrict__ stats,
    unsigned* __restrict__ bars,
    _Float16* __restrict__ scr,
    int mode,
    const float* __restrict__ fcW,
    const float* __restrict__ fcb,
    float* __restrict__ out)
{
  extern __shared__ _Float16 hS[];    // [2 planes][16 rows][SH]
  __shared__ unsigned sMeta[2];       // [slot, xcc]
  const int tid = threadIdx.x;
  const int wgid = blockIdx.x;
  const int wid = tid >> 6;            // 0..7 = 16-col tile
  const int lane = tid & 63;
  const int c16 = lane & 15;
  const int klo = lane >> 4;

  // ---- self-organize by physical XCD (validated; r15-proven mechanism) ----
  if (tid == 0) {
    unsigned xcc = __builtin_amdgcn_s_getreg((3 << 11) | 20) & 15u;  // HW_REG_XCC_ID
    unsigned slot = __hip_atomic_fetch_add(&bars[1536 + (xcc & 7u)], 1u,
                                           __ATOMIC_RELAXED, __HIP_MEMORY_SCOPE_AGENT);
    if (slot >= 32u || xcc > 7u)
      __hip_atomic_fetch_or(&bars[1544], 1u, __ATOMIC_ACQ_REL, __HIP_MEMORY_SCOPE_SYSTEM);
    sMeta[0] = slot; sMeta[1] = xcc & 7u;
  }
  unsigned ep = 1;
  gridbar256(bars, wgid, tid, ep);
  const unsigned bad = __hip_atomic_load(&bars[1544], __ATOMIC_ACQUIRE, __HIP_MEMORY_SCOPE_SYSTEM);
  const bool fast = (mode != 0) && (bad == 0u);
  // fast mapping == r14's weight-local layout, placement-verified:
  const int mtile  = fast ? (int)(sMeta[0] >> 2) : (wgid >> 5);
  const int colgrp = fast ? (int)((sMeta[0] & 3u) * 8u + sMeta[1]) : (wgid & 31);
  const int sib    = colgrp >> 3;                     // 0..3
  const int xm     = fast ? (int)(sMeta[1] * 8u + (unsigned)mtile) : 0;
  _Float16* scrb   = scr + (size_t)xm * 65536;        // [2][16][2048] fp16
  const int rowbase = mtile * 16;

  const int gp = colgrp * 128 + wid * 16 + c16;
  const float b0v  = vecs[gp];
  const float g0v  = vecs[4096 + gp];
  const float be0v = vecs[8192 + gp];
  const float b1v  = vecs[12288 + gp];
  const float g1v  = vecs[16384 + gp];
  const float be1v = vecs[20480 + gp];

  const int arow = rowbase + c16;
  const float* xbase = x + (size_t)arow * 512 * 512; // x[row][t][d]
  const _Float16* w0a = W0ap + (size_t)gp * 1536;
  const _Float16* w0b = W0bp + (size_t)gp * 1536;
  const _Float16* w1a = W1ap + (size_t)gp * 2048;
  const _Float16* w1b = W1bp + (size_t)gp * 2048;
  const int repbase = (colgrp & 15) << 2;            // rep*4 for stats writes
  const int cbase = colgrp * 32 + wid * 4;           // h-unit base for this wave

  float c0s[4] = {0,0,0,0};
  float c1s[4] = {0,0,0,0};
  half8_t stg[16];
  unsigned sep = 0;

#define LIN_DECODE(J)                                                         \
      int linear = tid + 512 * (J);                                           \
      int plane = linear >> 12;                                               \
      int rem = linear & 4095;                                                \
      int row = rem >> 8;                                                     \
      int ck  = rem & 255;

// ---- fallback stage (r14): all 16 chunks SYSTEM, compiler-tracked
#define STAGE_ISSUE() {                                                       \
    _Pragma("unroll")                                                         \
    for (int j = 0; j < 16; ++j) {                                            \
      LIN_DECODE(j)                                                           \
      const _Float16* srcp = (plane ? hcm : hch)                              \
                           + (size_t)(rowbase + row) * 2048 + ck * 8;         \
      stg[j] = ld_h8_coh(srcp);                                               \
    } }

#define STAGE_COMMIT() {                                                      \
    _Pragma("unroll")                                                         \
    for (int j = 0; j < 16; ++j) {                                            \
      LIN_DECODE(j)                                                           \
      *(half8_t*)&hS[plane * HMOFF + row * SH + ck * 8] = stg[j];             \
    }                                                                         \
    __syncthreads(); }

// ---- fast stage pieces: quarter SYSTEM issue / commit-to-scr / L2 gather
#define QSTAGE_ISSUE() {                                                      \
    _Pragma("unroll")                                                         \
    for (int jj = 0; jj < 4; ++jj) {                                          \
      LIN_DECODE(sib * 4 + jj)                                                \
      const _Float16* srcp = (plane ? hcm : hch)                              \
                           + (size_t)(rowbase + row) * 2048 + ck * 8;         \
      stg[jj] = ld_h8_coh(srcp);                                              \
    } }

#define QSTAGE_TO_SCR() {                                                     \
    _Pragma("unroll")                                                         \
    for (int jj = 0; jj < 4; ++jj) {                                          \
      LIN_DECODE(sib * 4 + jj)                                                \
      *(half8_t*)&scrb[plane * 32768 + row * 2048 + ck * 8] = stg[jj];        \
    }                                                                         \
    asm volatile("s_waitcnt vmcnt(0)" ::: "memory"); }

#define SCR_GATHER() {                                                        \
    _Pragma("unroll")                                                         \
    for (int j = 0; j < 16; ++j) {                                            \
      LIN_DECODE(j)                                                           \
      stg[j] = ld_h8_l2(&scrb[plane * 32768 + row * 2048 + ck * 8]);          \
    }                                                                         \
    asm volatile("s_waitcnt vmcnt(0)" ::: "memory");                          \
    __builtin_amdgcn_sched_barrier(0);                                        \
    _Pragma("unroll")                                                         \
    for (int j = 0; j < 16; ++j) {                                            \
      LIN_DECODE(j)                                                           \
      *(half8_t*)&hS[plane * HMOFF + row * SH + ck * 8] = stg[j];             \
    }                                                                         \
    __syncthreads(); }

#define SPLIT2(E, J) { float e_ = (E); _Float16 h1_ = (_Float16)e_;           \
  float r_ = e_ - (float)h1_; ah[J] = h1_; am[J] = (_Float16)(r_ * 2048.0f); }

#define PROD3(HA, MA) \
  HA = MFMA16(ah, bh0, HA);                                                   \
  MA = MFMA16(ah, bm0, MA);                                                   \
  MA = MFMA16(am, bh0, MA);

#define X_BODY(KB, HA, MA) {                                                  \
      float4 xu = *(const float4*)(xp + (KB) * 32);                           \
      float4 xw = *(const float4*)(xp + (KB) * 32 + 4);                       \
      half8_t ah, am;                                                         \
      SPLIT2(xu.x, 0) SPLIT2(xu.y, 1) SPLIT2(xu.z, 2) SPLIT2(xu.w, 3)         \
      SPLIT2(xw.x, 4) SPLIT2(xw.y, 5) SPLIT2(xw.z, 6) SPLIT2(xw.w, 7)         \
      half8_t bh0 = *(const half8_t*)&w0a[(KB) * 32 + klo * 8];               \
      half8_t bm0 = *(const half8_t*)&w0b[(KB) * 32 + klo * 8];               \
      PROD3(HA, MA) }

#define H0_BODY(KB, HA, MA) {                                                 \
      half8_t ah = *(const half8_t*)&hS[c16 * SH + (KB) * 32 + klo * 8];      \
      half8_t am = *(const half8_t*)&hS[HMOFF + c16 * SH + (KB) * 32 + klo * 8]; \
      half8_t bh0 = *(const half8_t*)&w0a[512 + (KB) * 32 + klo * 8];         \
      half8_t bm0 = *(const half8_t*)&w0b[512 + (KB) * 32 + klo * 8];         \
      PROD3(HA, MA) }

#define H1_BODY(KB, HA, MA) {                                                 \
      half8_t ah = *(const half8_t*)&hS[c16 * SH + (KB) * 32 + klo * 8];      \
      half8_t am = *(const half8_t*)&hS[HMOFF + c16 * SH + (KB) * 32 + klo * 8]; \
      half8_t bh0 = *(const half8_t*)&w1a[(KB) * 32 + klo * 8];               \
      half8_t bm0 = *(const half8_t*)&w1b[(KB) * 32 + klo * 8];               \
      PROD3(HA, MA) }

#define STAT_ADD(V, BUF) {                                                    \
    _Pragma("unroll")                                                         \
    for (int r = 0; r < 4; ++r) {                                             \
      float s = V[r];                                                         \
      float q = V[r]*V[r];                                                    \
      _Pragma("unroll")                                                       \
      for (int m = 1; m <= 8; m <<= 1) { s += __shfl_xor(s, m); q += __shfl_xor(q, m); } \
      if (c16 == 0) {                                                         \
        int row = rowbase + klo * 4 + r;                                      \
        atomicAdd(&stats[(repbase + (BUF)) * 256 + row * 2 + 0], s);          \
        atomicAdd(&stats[(repbase + (BUF)) * 256 + row * 2 + 1], q);          \
      }                                                                       \
    } }

#define CELL(V, BUF, CS, GC, BEC, HB) {                                       \
    _Pragma("unroll")                                                         \
    for (int r = 0; r < 4; ++r) {                                             \
      int row = rowbase + klo * 4 + r;                                        \
      const float* sp = stats + ((c16 << 2) + (BUF)) * 256 + row * 2;         \
      float s_ = ld_f_coh(sp), q_ = ld_f_coh(sp + 1);                         \
      _Pragma("unroll")                                                       \
      for (int m = 1; m <= 8; m <<= 1) { s_ += __shfl_xor(s_, m); q_ += __shfl_xor(q_, m); } \
      float mean = s_ * (1.0f / 4096.0f);                                     \
      float msq  = q_ * (1.0f / 4096.0f);                                     \
      float rstd = rsqrtf(msq - mean * mean + 1e-5f);                         \
      float gh = (V[r] - mean) * rstd * GC + BEC;                             \
      float fg = __shfl_down(gh, 4);                                          \
      float gg = __shfl_down(gh, 8);                                          \
      float og = __shfl_down(gh, 12);                                         \
      if (c16 < 4) {                                                          \
        float iv = sigm(gh), fv = sigm(fg), zv = tanh_fast(gg), ov = sigm(og); \
        float cc = fv * CS[r] + iv * zv;                                      \
        CS[r] = cc;                                                           \
        float hv = ov * tanh_fast(cc);                                        \
        int idx = row * 2048 + (HB) + cbase + c16;                            \
        _Float16 h1v = (_Float16)hv;                                          \
        st_h_coh(&hch[idx], h1v);                                             \
        st_h_coh(&hcm[idx], (_Float16)((hv - (float)h1v) * 2048.0f));         \
      }                                                                       \
    } }

  f32x4_t ahe, aho, ame, amo;     // layer-0 accumulators
  f32x4_t dhe, dho, dme, dmo;     // layer-1 accumulators
  f32x4_t a0, d0;

#define A0_X(TT) {                                                            \
    ahe = {0,0,0,0}; aho = {0,0,0,0}; ame = {0,0,0,0}; amo = {0,0,0,0};       \
    const float* xp = xbase + (size_t)(TT) * 512 + klo * 8;                   \
    _Pragma("unroll 2")                                                       \
    for (int kb = 0; kb < 16; kb += 2) {                                      \
      X_BODY(kb,     ahe, ame);                                               \
      X_BODY(kb + 1, aho, amo);                                               \
    } }

#define A0_COMBINE() {                                                        \
    a0 = (ahe + aho) * 0.03125f + (ame + amo) * (1.0f / 65536.0f);            \
    _Pragma("unroll")                                                         \
    for (int r_ = 0; r_ < 4; ++r_) a0[r_] += b0v; }

// one full stage (fast or fallback), with A0_X(t+1) overlapped when DO_X
#define STAGE_ALL(DO_X, TT) {                                                 \
    if (fast) {                                                               \
      QSTAGE_ISSUE();                                                         \
      if (DO_X) A0_X(TT);                                                     \
      QSTAGE_TO_SCR();                                                        \
      sibbar(bars, xm, tid, ++sep);                                           \
      SCR_GATHER();                                                           \
    } else {                                                                  \
      STAGE_ISSUE();                                                          \
      if (DO_X) A0_X(TT);                                                     \
      STAGE_COMMIT();                                                         \
    } }

  // ---------------- prologue: A0[0] (h planes are zeroed) ----------------
  STAGE_ALL(0, 0);
  A0_X(0);
  #pragma unroll 2
  for (int kb = 0; kb < 32; kb += 2) {
    H0_BODY(kb,     ahe, ame);
    H0_BODY(kb + 1, aho, amo);
  }
  A0_COMBINE();
  STAT_ADD(a0, 0);
  groupbar(bars, mtile, tid, ++ep);
  CELL(a0, 0, c0s, g0v, be0v, 0);
  groupbar(bars, mtile, tid, ++ep);

  // ---------------- main loop ----------------
  for (int t = 0; t < 512; ++t) {
    const int par = t & 1;
    const int npar = 1 - par;

    // ===== alpha[t]: stage {h0[t], h1[t-1]} (A0_X(t+1) overlapped) =====
    if (t < 511) { STAGE_ALL(1, t + 1); }
    else         { STAGE_ALL(0, 0); }

    dhe = {0,0,0,0}; dho = {0,0,0,0}; dme = {0,0,0,0}; dmo = {0,0,0,0};
    if (t < 511) {
      // fused H1 + A0_H0 (2 independent weight streams; r13/r14 chain order)
      #pragma unroll 2
      for (int i = 0; i < 32; i += 2) {
        H1_BODY(2*i,     dhe, dme);
        H1_BODY(2*i+1,   dho, dmo);
        H0_BODY(i,       ahe, ame);
        H1_BODY(2*i+2,   dhe, dme);
        H1_BODY(2*i+3,   dho, dmo);
        H0_BODY(i+1,     aho, amo);
      }
    } else {
      #pragma unroll 2
      for (int kb = 0; kb < 64; kb += 2) {
        H1_BODY(kb,     dhe, dme);
        H1_BODY(kb + 1, dho, dmo);
      }
    }
    d0 = (dhe + dho) * 0.03125f + (dme + dmo) * (1.0f / 65536.0f);
    #pragma unroll
    for (int r = 0; r < 4; ++r) d0[r] += b1v;
    STAT_ADD(d0, 2 + par);

    if (t < 511) {
      A0_COMBINE();
      STAT_ADD(a0, npar);
    }

    // group-local stats zeroing
    if (colgrp < 16 && tid < 64) {
      int bufsel = ((tid >> 5) == 0) ? (2 + npar) : par;
      st_f_coh(&stats[((colgrp << 2) + bufsel) * 256 + mtile * 32 + (tid & 31)], 0.0f);
    }

    groupbar(bars, mtile, tid, ++ep);

    // ===== beta[t]: B1[t] (+ B0[t+1]) =====
    CELL(d0, 2 + par, c1s, g1v, be1v, 1024);
    if (t < 511) {
      CELL(a0, npar, c0s, g0v, be0v, 0);
    }
    groupbar(bars, mtile, tid, ++ep);
  }

  // ---------------- final fc (group-local): rows of this mtile ----------
  {
    if (tid < 256) {
      int b = rowbase + (tid >> 4);
      int o = colgrp * 16 + (tid & 15);
      const _Float16* p1 = hch + (size_t)b * 2048 + 1024;
      const _Float16* p2 = hcm + (size_t)b * 2048 + 1024;
      float s = fcb[o];
      #pragma unroll 4
      for (int k = 0; k < 1024; k += 4) {
        union { u64 q; _Float16 h[4]; } ua, um;
        ua.q = __hip_atomic_load((u64*)(p1 + k), __ATOMIC_RELAXED, __HIP_MEMORY_SCOPE_SYSTEM);
        um.q = __hip_atomic_load((u64*)(p2 + k), __ATOMIC_RELAXED, __HIP_MEMORY_SCOPE_SYSTEM);
        #pragma unroll
        for (int i = 0; i < 4; ++i) {
          float h = (float)ua.h[i] + (float)um.h[i] * (1.0f / 2048.0f);
          s = fmaf(h, fcW[(k + i) * 512 + o], s);
        }
      }
      out[b * 512 + o] = s;
    }
  }
}

extern "C" void kernel_launch(void* const* d_in, const int* in_sizes, int n_in,
                              void* d_out, int out_size, void* d_ws, size_t ws_size,
                              hipStream_t stream) {
  const float* x   = (const float*)d_in[0];
  const float* W0  = (const float*)d_in[1];
  const float* b0  = (const float*)d_in[2];
  const float* g0  = (const float*)d_in[3];
  const float* be0 = (const float*)d_in[4];
  const float* W1  = (const float*)d_in[5];
  const float* b1  = (const float*)d_in[6];
  const float* g1  = (const float*)d_in[7];
  const float* be1 = (const float*)d_in[8];
  const float* fcW = (const float*)d_in[9];
  const float* fcb = (const float*)d_in[10];
  float* out = (float*)d_out;

  char* ws = (char*)d_ws;
  _Float16* W0a  = (_Float16*)(ws);
  _Float16* W0b  = (_Float16*)(ws + 12582912);
  _Float16* W1a  = (_Float16*)(ws + 25165824);
  _Float16* W1b  = (_Float16*)(ws + 41943040);
  float* vecs    = (float*)(ws + 58720256);
  _Float16* hch  = (_Float16*)(ws + 58818560);
  _Float16* hcm  = (_Float16*)(ws + 59342848);
  float* stats   = (float*)(ws + 59867136);
  unsigned* bars = (unsigned*)(ws + 59932672);
  _Float16* scr  = (_Float16*)(ws + WS_BASE);

  // sibling-scratch scheme only if the workspace can hold it
  int mode = (ws_size >= (size_t)WS_BASE + SCR_BYTES) ? 1 : 0;

  // re-zero h planes + stats + barrier/slot state every call (graph replays)
  hipMemsetAsync(hch, 0, 524288 + 524288 + 65536 + 8192, stream);
  lstm_prep<<<7264, 256, 0, stream>>>(W0, W1, b0, g0, be0, b1, g1, be1,
                                      W0a, W0b, W1a, W1b, vecs);

  hipFuncSetAttribute((const void*)lstm_seq,
                      hipFuncAttributeMaxDynamicSharedMemorySize, LDS_BYTES);
  void* args[] = { (void*)&x, (void*)&W0a, (void*)&W0b, (void*)&W1a, (void*)&W1b,
                   (void*)&vecs, (void*)&hch, (void*)&hcm,
                   (void*)&stats, (void*)&bars, (void*)&scr, (void*)&mode,
                   (void*)&fcW, (void*)&fcb, (void*)&out };
  hipError_t lerr = hipLaunchCooperativeKernel((const void*)lstm_seq,
                                               dim3(256), dim3(512),
                                               args, LDS_BYTES, stream);
  if (lerr != hipSuccess) {
    (void)hipGetLastError();
    lstm_seq<<<dim3(256), dim3(512), LDS_BYTES, stream>>>(
        x, W0a, W0b, W1a, W1b, vecs, hch, hcm, stats, bars, scr, mode,
        fcW, fcb, out);
  }
}

// Round 17
// 36257.370 us; speedup vs baseline: 1.2352x; 1.1504x over previous
//
#include <hip/hip_runtime.h>
#include <hip/hip_bf16.h>

typedef __attribute__((ext_vector_type(8))) _Float16 half8_t;
typedef __attribute__((ext_vector_type(4))) float f32x4_t;
typedef unsigned long long u64;

#define SH 2056                       // LDS h row stride (elems): 2048 + 8
#define HMOFF (16 * SH)               // plane-2 offset (elems)
#define LDS_BYTES (2 * 16 * SH * 2)   // 131,584 B -> 1 WG/CU, 8 waves = 2/SIMD

__device__ __forceinline__ float sigm(float z) { return 1.0f / (1.0f + __expf(-z)); }
__device__ __forceinline__ float tanh_fast(float z) {
  float e = __expf(2.0f * z);
  return 1.0f - 2.0f / (e + 1.0f);
}

// ---- coherent (cross-XCD) access helpers (SYSTEM scope)
__device__ __forceinline__ half8_t ld_h8_coh(const _Float16* p) {
  union { half8_t h; u64 q[2]; } r;
  u64* q = (u64*)p;
  r.q[0] = __hip_atomic_load(q,     __ATOMIC_RELAXED, __HIP_MEMORY_SCOPE_SYSTEM);
  r.q[1] = __hip_atomic_load(q + 1, __ATOMIC_RELAXED, __HIP_MEMORY_SCOPE_SYSTEM);
  return r.h;
}
__device__ __forceinline__ void st_h_coh(_Float16* p, _Float16 v) {
  unsigned short b = __builtin_bit_cast(unsigned short, v);
  __hip_atomic_store((unsigned short*)p, b, __ATOMIC_RELAXED, __HIP_MEMORY_SCOPE_SYSTEM);
}
__device__ __forceinline__ float ld_f_coh(const float* p) {
  return __hip_atomic_load((float*)p, __ATOMIC_RELAXED, __HIP_MEMORY_SCOPE_SYSTEM);
}
__device__ __forceinline__ void st_f_coh(float* p, float v) {
  __hip_atomic_store(p, v, __ATOMIC_RELAXED, __HIP_MEMORY_SCOPE_SYSTEM);
}

// ws layout (bytes) — total 59,940,864 (r10..r14 known-good):
//   W0a  @ 0         : 12582912   (fp16 plane1 = fp16(32*w), [gp][k])
//   W0b  @ 12582912  : 12582912
//   W1a  @ 25165824  : 16777216
//   W1b  @ 41943040  : 16777216
//   vecs @ 58720256  : 98304
//   hch  @ 58818560  : 524288     (h plane1 fp16, [row][h0|h1])
//   hcm  @ 59342848  : 524288     (h plane2 fp16, residual*2048)
//   stats@ 59867136  : 65536      (16 reps x 4 bufs x 256 f32)
//   bars @ 59932672  : 8192

// permutation (128-col WG groups): gp = colgrp*128 + w*16 + c,
//   gate = c>>2, uo = c&3 ; gcol = gate*1024 + colgrp*32 + w*4 + uo
__global__ void lstm_prep(const float* __restrict__ W0, const float* __restrict__ W1,
                          const float* __restrict__ b0, const float* __restrict__ g0,
                          const float* __restrict__ be0, const float* __restrict__ b1,
                          const float* __restrict__ g1, const float* __restrict__ be1,
                          _Float16* __restrict__ W0a, _Float16* __restrict__ W0b,
                          _Float16* __restrict__ W1a, _Float16* __restrict__ W1b,
                          float* __restrict__ vecs)
{
  int gid = blockIdx.x * 256 + threadIdx.x;
  const int W0N = 192 * 4096;
  const int W1N = 256 * 4096;
  if (gid < W0N) {
    int k8 = gid >> 12, gp = gid & 4095;
    int colgrp = gp >> 7, w = (gp >> 4) & 7, c = gp & 15;
    int gcol = ((c >> 2) << 10) + (colgrp << 5) + (w << 2) + (c & 3);
    half8_t va, vb;
    #pragma unroll
    for (int j = 0; j < 8; ++j) {
      float w32 = W0[(size_t)(k8 * 8 + j) * 4096 + gcol] * 32.0f;
      _Float16 p1 = (_Float16)w32;
      float r = w32 - (float)p1;
      va[j] = p1; vb[j] = (_Float16)(r * 2048.0f);
    }
    *(half8_t*)&W0a[(size_t)gp * 1536 + k8 * 8] = va;
    *(half8_t*)&W0b[(size_t)gp * 1536 + k8 * 8] = vb;
  } else if (gid < W0N + W1N) {
    int g2 = gid - W0N;
    int k8 = g2 >> 12, gp = g2 & 4095;
    int colgrp = gp >> 7, w = (gp >> 4) & 7, c = gp & 15;
    int gcol = ((c >> 2) << 10) + (colgrp << 5) + (w << 2) + (c & 3);
    half8_t va, vb;
    #pragma unroll
    for (int j = 0; j < 8; ++j) {
      float w32 = W1[(size_t)(k8 * 8 + j) * 4096 + gcol] * 32.0f;
      _Float16 p1 = (_Float16)w32;
      float r = w32 - (float)p1;
      va[j] = p1; vb[j] = (_Float16)(r * 2048.0f);
    }
    *(half8_t*)&W1a[(size_t)gp * 2048 + k8 * 8] = va;
    *(half8_t*)&W1b[(size_t)gp * 2048 + k8 * 8] = vb;
  } else if (gid < W0N + W1N + 6 * 4096) {
    int g2 = gid - W0N - W1N;
    int j = g2 >> 12, gp = g2 & 4095;
    int colgrp = gp >> 7, w = (gp >> 4) & 7, c = gp & 15;
    int gcol = ((c >> 2) << 10) + (colgrp << 5) + (w << 2) + (c & 3);
    const float* src = (j == 0) ? b0 : (j == 1) ? g0 : (j == 2) ? be0
                     : (j == 3) ? b1 : (j == 4) ? g1 : be1;
    vecs[j * 4096 + gp] = src[gcol];
  }
}

#define MFMA16(A, B, C) __builtin_amdgcn_mfma_f32_16x16x32_f16(A, B, C, 0, 0, 0)

// ---- GROUP-LOCAL barrier: 32 arrivals (one mtile group)
__device__ __forceinline__ void groupbar(unsigned* bars, int grp, int tid, unsigned ep) {
  __syncthreads();
  if (tid == 0) {
    const int q = ep & 1;
    unsigned old = __hip_atomic_fetch_add(&bars[(grp * 2 + q) * 32], 1u,
                                          __ATOMIC_RELAXED, __HIP_MEMORY_SCOPE_AGENT);
    if (old == 31u) {
      __hip_atomic_store(&bars[(grp * 2 + q) * 32], 0u, __ATOMIC_RELAXED, __HIP_MEMORY_SCOPE_SYSTEM);
      __hip_atomic_store(&bars[1024 + grp * 32], ep, __ATOMIC_RELEASE, __HIP_MEMORY_SCOPE_SYSTEM);
    }
    while (__hip_atomic_load(&bars[1024 + grp * 32], __ATOMIC_RELAXED, __HIP_MEMORY_SCOPE_SYSTEM) < ep) {}
  }
  __syncthreads();
}

// 256 WGs x 512 thr (r14 structure). WG = (mtile = wgid>>5, colgrp = wgid&31);
// wave wid = 16-col tile. SPLIT-STAGE pipelining: issue all h loads (h0-half
// first), overlap with A0_X; commit h0 -> compute H1[0..31]+H0[0..31] (1:1)
// while the h1-half loads stay in flight; commit h1 -> H1[32..63].
__global__ void __launch_bounds__(512, 2) lstm_seq(
    const float* __restrict__ x,
    const _Float16* __restrict__ W0ap,
    const _Float16* __restrict__ W0bp,
    const _Float16* __restrict__ W1ap,
    const _Float16* __restrict__ W1bp,
    const float* __restrict__ vecs,
    _Float16* __restrict__ hch,
    _Float16* __restrict__ hcm,
    float* __restrict__ stats,
    unsigned* __restrict__ bars,
    const float* __restrict__ fcW,
    const float* __restrict__ fcb,
    float* __restrict__ out)
{
  extern __shared__ _Float16 hS[];    // [2 planes][16 rows][SH]
  const int tid = threadIdx.x;
  const int wgid = blockIdx.x;
  const int mtile = wgid >> 5;         // 0..7 = group
  const int colgrp = wgid & 31;        // 0..31 (128-col group)
  const int wid = tid >> 6;            // 0..7 = 16-col tile
  const int lane = tid & 63;
  const int c16 = lane & 15;
  const int klo = lane >> 4;
  const int rowbase = mtile * 16;

  const int gp = colgrp * 128 + wid * 16 + c16;
  const float b0v  = vecs[gp];
  const float g0v  = vecs[4096 + gp];
  const float be0v = vecs[8192 + gp];
  const float b1v  = vecs[12288 + gp];
  const float g1v  = vecs[16384 + gp];
  const float be1v = vecs[20480 + gp];

  const int arow = rowbase + c16;
  const float* xbase = x + (size_t)arow * 512 * 512; // x[row][t][d]
  const _Float16* w0a = W0ap + (size_t)gp * 1536;
  const _Float16* w0b = W0bp + (size_t)gp * 1536;
  const _Float16* w1a = W1ap + (size_t)gp * 2048;
  const _Float16* w1b = W1bp + (size_t)gp * 2048;
  const int repbase = (colgrp & 15) << 2;            // rep*4 for stats writes
  const int cbase = colgrp * 32 + wid * 4;           // h-unit base for this wave

  float c0s[4] = {0,0,0,0};
  float c1s[4] = {0,0,0,0};
  unsigned ep = 0;
  half8_t stg[16];                    // in-flight stage registers

// half-stage decode: idx in [0,4096) -> (plane, row, ck128). HALF=0 -> h0
// columns (ck 0..127); HALF=1 -> h1 columns (ck 128..255).
#define HDECODE(Q)                                                            \
      int idx = tid + 512 * (Q);                                              \
      int plane = idx >> 11;                                                  \
      int rem = idx & 2047;                                                   \
      int row = rem >> 7;                                                     \
      int ckk = rem & 127;

// issue: h0 chunks into stg[0..7] FIRST, then h1 chunks into stg[8..15]
#define STAGE_ISSUE_ALL() {                                                   \
    _Pragma("unroll")                                                         \
    for (int q = 0; q < 8; ++q) {                                             \
      HDECODE(q)                                                              \
      const _Float16* srcp = (plane ? hcm : hch)                              \
                           + (size_t)(rowbase + row) * 2048 + ckk * 8;        \
      stg[q] = ld_h8_coh(srcp);                                               \
    }                                                                         \
    _Pragma("unroll")                                                         \
    for (int q = 0; q < 8; ++q) {                                             \
      HDECODE(q)                                                              \
      const _Float16* srcp = (plane ? hcm : hch)                              \
                           + (size_t)(rowbase + row) * 2048 + 1024 + ckk * 8; \
      stg[8 + q] = ld_h8_coh(srcp);                                           \
    } }

#define STAGE_COMMIT_H0() {                                                   \
    _Pragma("unroll")                                                         \
    for (int q = 0; q < 8; ++q) {                                             \
      HDECODE(q)                                                              \
      *(half8_t*)&hS[plane * HMOFF + row * SH + ckk * 8] = stg[q];            \
    }                                                                         \
    __syncthreads(); }

#define STAGE_COMMIT_H1() {                                                   \
    _Pragma("unroll")                                                         \
    for (int q = 0; q < 8; ++q) {                                             \
      HDECODE(q)                                                              \
      *(half8_t*)&hS[plane * HMOFF + row * SH + 1024 + ckk * 8] = stg[8 + q]; \
    }                                                                         \
    __syncthreads(); }

#define SPLIT2(E, J) { float e_ = (E); _Float16 h1_ = (_Float16)e_;           \
  float r_ = e_ - (float)h1_; ah[J] = h1_; am[J] = (_Float16)(r_ * 2048.0f); }

#define PROD3(HA, MA) \
  HA = MFMA16(ah, bh0, HA);                                                   \
  MA = MFMA16(ah, bm0, MA);                                                   \
  MA = MFMA16(am, bh0, MA);

#define X_BODY(KB, HA, MA) {                                                  \
      float4 xu = *(const float4*)(xp + (KB) * 32);                           \
      float4 xw = *(const float4*)(xp + (KB) * 32 + 4);                       \
      half8_t ah, am;                                                         \
      SPLIT2(xu.x, 0) SPLIT2(xu.y, 1) SPLIT2(xu.z, 2) SPLIT2(xu.w, 3)         \
      SPLIT2(xw.x, 4) SPLIT2(xw.y, 5) SPLIT2(xw.z, 6) SPLIT2(xw.w, 7)         \
      half8_t bh0 = *(const half8_t*)&w0a[(KB) * 32 + klo * 8];               \
      half8_t bm0 = *(const half8_t*)&w0b[(KB) * 32 + klo * 8];               \
      PROD3(HA, MA) }

#define H0_BODY(KB, HA, MA) {                                                 \
      half8_t ah = *(const half8_t*)&hS[c16 * SH + (KB) * 32 + klo * 8];      \
      half8_t am = *(const half8_t*)&hS[HMOFF + c16 * SH + (KB) * 32 + klo * 8]; \
      half8_t bh0 = *(const half8_t*)&w0a[512 + (KB) * 32 + klo * 8];         \
      half8_t bm0 = *(const half8_t*)&w0b[512 + (KB) * 32 + klo * 8];         \
      PROD3(HA, MA) }

#define H1_BODY(KB, HA, MA) {                                                 \
      half8_t ah = *(const half8_t*)&hS[c16 * SH + (KB) * 32 + klo * 8];      \
      half8_t am = *(const half8_t*)&hS[HMOFF + c16 * SH + (KB) * 32 + klo * 8]; \
      half8_t bh0 = *(const half8_t*)&w1a[(KB) * 32 + klo * 8];               \
      half8_t bm0 = *(const half8_t*)&w1b[(KB) * 32 + klo * 8];               \
      PROD3(HA, MA) }

#define STAT_ADD(V, BUF) {                                                    \
    _Pragma("unroll")                                                         \
    for (int r = 0; r < 4; ++r) {                                             \
      float s = V[r];                                                         \
      float q = V[r]*V[r];                                                    \
      _Pragma("unroll")                                                       \
      for (int m = 1; m <= 8; m <<= 1) { s += __shfl_xor(s, m); q += __shfl_xor(q, m); } \
      if (c16 == 0) {                                                         \
        int row = rowbase + klo * 4 + r;                                      \
        atomicAdd(&stats[(repbase + (BUF)) * 256 + row * 2 + 0], s);          \
        atomicAdd(&stats[(repbase + (BUF)) * 256 + row * 2 + 1], q);          \
      }                                                                       \
    } }

// LN + LSTM cell. Stats read: lane c16 loads replica c16, shuffle-sum (16 reps).
#define CELL(V, BUF, CS, GC, BEC, HB) {                                       \
    _Pragma("unroll")                                                         \
    for (int r = 0; r < 4; ++r) {                                             \
      int row = rowbase + klo * 4 + r;                                        \
      const float* sp = stats + ((c16 << 2) + (BUF)) * 256 + row * 2;         \
      float s_ = ld_f_coh(sp), q_ = ld_f_coh(sp + 1);                         \
      _Pragma("unroll")                                                       \
      for (int m = 1; m <= 8; m <<= 1) { s_ += __shfl_xor(s_, m); q_ += __shfl_xor(q_, m); } \
      float mean = s_ * (1.0f / 4096.0f);                                     \
      float msq  = q_ * (1.0f / 4096.0f);                                     \
      float rstd = rsqrtf(msq - mean * mean + 1e-5f);                         \
      float gh = (V[r] - mean) * rstd * GC + BEC;                             \
      float fg = __shfl_down(gh, 4);                                          \
      float gg = __shfl_down(gh, 8);                                          \
      float og = __shfl_down(gh, 12);                                         \
      if (c16 < 4) {                                                          \
        float iv = sigm(gh), fv = sigm(fg), zv = tanh_fast(gg), ov = sigm(og); \
        float cc = fv * CS[r] + iv * zv;                                      \
        CS[r] = cc;                                                           \
        float hv = ov * tanh_fast(cc);                                        \
        int idx = row * 2048 + (HB) + cbase + c16;                            \
        _Float16 h1v = (_Float16)hv;                                          \
        st_h_coh(&hch[idx], h1v);                                             \
        st_h_coh(&hcm[idx], (_Float16)((hv - (float)h1v) * 2048.0f));         \
      }                                                                       \
    } }

  f32x4_t ahe, aho, ame, amo;     // layer-0 accumulators
  f32x4_t dhe, dho, dme, dmo;     // layer-1 accumulators
  f32x4_t a0, d0;

#define A0_X(TT) {                                                            \
    ahe = {0,0,0,0}; aho = {0,0,0,0}; ame = {0,0,0,0}; amo = {0,0,0,0};       \
    const float* xp = xbase + (size_t)(TT) * 512 + klo * 8;                   \
    _Pragma("unroll 2")                                                       \
    for (int kb = 0; kb < 16; kb += 2) {                                      \
      X_BODY(kb,     ahe, ame);                                               \
      X_BODY(kb + 1, aho, amo);                                               \
    } }

#define A0_COMBINE() {                                                        \
    a0 = (ahe + aho) * 0.03125f + (ame + amo) * (1.0f / 65536.0f);            \
    _Pragma("unroll")                                                         \
    for (int r_ = 0; r_ < 4; ++r_) a0[r_] += b0v; }

  // ---------------- prologue: A0[0] (h planes are zeroed) ----------------
  STAGE_ISSUE_ALL();
  STAGE_COMMIT_H0();
  STAGE_COMMIT_H1();
  A0_X(0);
  #pragma unroll 2
  for (int kb = 0; kb < 32; kb += 2) {
    H0_BODY(kb,     ahe, ame);
    H0_BODY(kb + 1, aho, amo);
  }
  A0_COMBINE();
  STAT_ADD(a0, 0);
  groupbar(bars, mtile, tid, ++ep);
  CELL(a0, 0, c0s, g0v, be0v, 0);
  groupbar(bars, mtile, tid, ++ep);

  // ---------------- main loop ----------------
  for (int t = 0; t < 512; ++t) {
    const int par = t & 1;
    const int npar = 1 - par;

    // ===== alpha[t]: split-stage pipeline =====
    STAGE_ISSUE_ALL();             // all 32 SYSTEM loads in flight (h0 first)
    if (t < 511) {
      A0_X(t + 1);                 // hidden under h-independent X-part
    }
    STAGE_COMMIT_H0();             // waits only the h0-half (vmcnt(16))

    dhe = {0,0,0,0}; dho = {0,0,0,0}; dme = {0,0,0,0}; dmo = {0,0,0,0};
    if (t < 511) {
      // part A: H1 kb 0..31 + H0 kb 0..31 (1:1 interleave; h0-region only).
      // h1-half loads still in flight underneath.
      #pragma unroll 2
      for (int i = 0; i < 32; i += 2) {
        H1_BODY(i,       dhe, dme);
        H1_BODY(i + 1,   dho, dmo);
        H0_BODY(i,       ahe, ame);
        H0_BODY(i + 1,   aho, amo);
      }
      STAGE_COMMIT_H1();           // h1-half now ready
      // part B: H1 kb 32..63 (h1-region)
      #pragma unroll 2
      for (int kb = 32; kb < 64; kb += 2) {
        H1_BODY(kb,     dhe, dme);
        H1_BODY(kb + 1, dho, dmo);
      }
    } else {
      #pragma unroll 2
      for (int kb = 0; kb < 32; kb += 2) {
        H1_BODY(kb,     dhe, dme);
        H1_BODY(kb + 1, dho, dmo);
      }
      STAGE_COMMIT_H1();
      #pragma unroll 2
      for (int kb = 32; kb < 64; kb += 2) {
        H1_BODY(kb,     dhe, dme);
        H1_BODY(kb + 1, dho, dmo);
      }
    }
    d0 = (dhe + dho) * 0.03125f + (dme + dmo) * (1.0f / 65536.0f);
    #pragma unroll
    for (int r = 0; r < 4; ++r) d0[r] += b1v;
    STAT_ADD(d0, 2 + par);

    if (t < 511) {
      A0_COMBINE();
      STAT_ADD(a0, npar);
    }

    // group-local stats zeroing
    if (colgrp < 16 && tid < 64) {
      int bufsel = ((tid >> 5) == 0) ? (2 + npar) : par;
      st_f_coh(&stats[((colgrp << 2) + bufsel) * 256 + mtile * 32 + (tid & 31)], 0.0f);
    }

    groupbar(bars, mtile, tid, ++ep);

    // ===== beta[t]: B1[t] (+ B0[t+1]) =====
    CELL(d0, 2 + par, c1s, g1v, be1v, 1024);
    if (t < 511) {
      CELL(a0, npar, c0s, g0v, be0v, 0);
    }
    groupbar(bars, mtile, tid, ++ep);
  }

  // ---------------- final fc (group-local): rows of this mtile ----------
  {
    if (tid < 256) {
      int b = rowbase + (tid >> 4);
      int o = colgrp * 16 + (tid & 15);
      const _Float16* p1 = hch + (size_t)b * 2048 + 1024;
      const _Float16* p2 = hcm + (size_t)b * 2048 + 1024;
      float s = fcb[o];
      #pragma unroll 4
      for (int k = 0; k < 1024; k += 4) {
        union { u64 q; _Float16 h[4]; } ua, um;
        ua.q = __hip_atomic_load((u64*)(p1 + k), __ATOMIC_RELAXED, __HIP_MEMORY_SCOPE_SYSTEM);
        um.q = __hip_atomic_load((u64*)(p2 + k), __ATOMIC_RELAXED, __HIP_MEMORY_SCOPE_SYSTEM);
        #pragma unroll
        for (int i = 0; i < 4; ++i) {
          float h = (float)ua.h[i] + (float)um.h[i] * (1.0f / 2048.0f);
          s = fmaf(h, fcW[(k + i) * 512 + o], s);
        }
      }
      out[b * 512 + o] = s;
    }
  }
}

extern "C" void kernel_launch(void* const* d_in, const int* in_sizes, int n_in,
                              void* d_out, int out_size, void* d_ws, size_t ws_size,
                              hipStream_t stream) {
  const float* x   = (const float*)d_in[0];
  const float* W0  = (const float*)d_in[1];
  const float* b0  = (const float*)d_in[2];
  const float* g0  = (const float*)d_in[3];
  const float* be0 = (const float*)d_in[4];
  const float* W1  = (const float*)d_in[5];
  const float* b1  = (const float*)d_in[6];
  const float* g1  = (const float*)d_in[7];
  const float* be1 = (const float*)d_in[8];
  const float* fcW = (const float*)d_in[9];
  const float* fcb = (const float*)d_in[10];
  float* out = (float*)d_out;

  char* ws = (char*)d_ws;
  _Float16* W0a  = (_Float16*)(ws);
  _Float16* W0b  = (_Float16*)(ws + 12582912);
  _Float16* W1a  = (_Float16*)(ws + 25165824);
  _Float16* W1b  = (_Float16*)(ws + 41943040);
  float* vecs    = (float*)(ws + 58720256);
  _Float16* hch  = (_Float16*)(ws + 58818560);
  _Float16* hcm  = (_Float16*)(ws + 59342848);
  float* stats   = (float*)(ws + 59867136);
  unsigned* bars = (unsigned*)(ws + 59932672);

  // re-zero h planes + stats + barrier state every call (graph replays reuse ws)
  hipMemsetAsync(hch, 0, 524288 + 524288 + 65536 + 8192, stream);
  lstm_prep<<<7264, 256, 0, stream>>>(W0, W1, b0, g0, be0, b1, g1, be1,
                                      W0a, W0b, W1a, W1b, vecs);

  hipFuncSetAttribute((const void*)lstm_seq,
                      hipFuncAttributeMaxDynamicSharedMemorySize, LDS_BYTES);
  void* args[] = { (void*)&x, (void*)&W0a, (void*)&W0b, (void*)&W1a, (void*)&W1b,
                   (void*)&vecs, (void*)&hch, (void*)&hcm,
                   (void*)&stats, (void*)&bars,
                   (void*)&fcW, (void*)&fcb, (void*)&out };
  hipError_t lerr = hipLaunchCooperativeKernel((const void*)lstm_seq,
                                               dim3(256), dim3(512),
                                               args, LDS_BYTES, stream);
  if (lerr != hipSuccess) {
    // coop validator rejected (>64KB-LDS occupancy calc). Grid=256 = #CUs at
    // 1 WG/CU -> co-residency capacity-guaranteed; plain launch + own barrier.
    (void)hipGetLastError();
    lstm_seq<<<dim3(256), dim3(512), LDS_BYTES, stream>>>(
        x, W0a, W0b, W1a, W1b, vecs, hch, hcm, stats, bars, fcW, fcb, out);
  }
}

// Round 18
// 35489.920 us; speedup vs baseline: 1.2619x; 1.0216x over previous
//
#include <hip/hip_runtime.h>
#include <hip/hip_bf16.h>

typedef __attribute__((ext_vector_type(8))) _Float16 half8_t;
typedef __attribute__((ext_vector_type(4))) float f32x4_t;
typedef __attribute__((ext_vector_type(4))) unsigned u32x4_t;
typedef unsigned long long u64;

#define SH 2056                       // LDS h row stride (elems): 2048 + 8
#define HMOFF (16 * SH)               // plane-2 offset (elems)
#define LDS_BYTES (2 * 16 * SH * 2)   // 131,584 B -> 1 WG/CU, 8 waves = 2/SIMD

__device__ __forceinline__ float sigm(float z) { return 1.0f / (1.0f + __expf(-z)); }
__device__ __forceinline__ float tanh_fast(float z) {
  float e = __expf(2.0f * z);
  return 1.0f - 2.0f / (e + 1.0f);
}

// ---- coherent helpers (SYSTEM scope, compiler-tracked) for small data
__device__ __forceinline__ float ld_f_coh(const float* p) {
  return __hip_atomic_load((float*)p, __ATOMIC_RELAXED, __HIP_MEMORY_SCOPE_SYSTEM);
}
__device__ __forceinline__ void st_f_coh(float* p, float v) {
  __hip_atomic_store(p, v, __ATOMIC_RELAXED, __HIP_MEMORY_SCOPE_SYSTEM);
}

// ---- WIDE coherent load: 16B, bypass L1+L2 (sc0 sc1). Non-atomic — we only
// need the cache-bypass semantics (r15-proven pattern). Must be followed by an
// explicit s_waitcnt before use.
__device__ __forceinline__ u32x4_t ld_u32x4_sys(const unsigned* p) {
  u32x4_t r;
  asm volatile("global_load_dwordx4 %0, %1, off sc0 sc1"
               : "=v"(r) : "v"(p) : "memory");
  return r;
}

// ws layout (bytes) — total 59,940,864 (r10..r17 known-good):
//   W0a  @ 0         : 12582912   (fp16 plane1 = fp16(32*w), [gp][k])
//   W0b  @ 12582912  : 12582912
//   W1a  @ 25165824  : 16777216
//   W1b  @ 41943040  : 16777216
//   vecs @ 58720256  : 98304
//   hpk  @ 58818560  : 1048576    (h PACKED u32 [row][2048]: lo16=p1, hi16=p2*2048)
//   stats@ 59867136  : 65536      (16 reps x 4 bufs x 256 f32)
//   bars @ 59932672  : 8192

// permutation (128-col WG groups): gp = colgrp*128 + w*16 + c,
//   gate = c>>2, uo = c&3 ; gcol = gate*1024 + colgrp*32 + w*4 + uo
__global__ void lstm_prep(const float* __restrict__ W0, const float* __restrict__ W1,
                          const float* __restrict__ b0, const float* __restrict__ g0,
                          const float* __restrict__ be0, const float* __restrict__ b1,
                          const float* __restrict__ g1, const float* __restrict__ be1,
                          _Float16* __restrict__ W0a, _Float16* __restrict__ W0b,
                          _Float16* __restrict__ W1a, _Float16* __restrict__ W1b,
                          float* __restrict__ vecs)
{
  int gid = blockIdx.x * 256 + threadIdx.x;
  const int W0N = 192 * 4096;
  const int W1N = 256 * 4096;
  if (gid < W0N) {
    int k8 = gid >> 12, gp = gid & 4095;
    int colgrp = gp >> 7, w = (gp >> 4) & 7, c = gp & 15;
    int gcol = ((c >> 2) << 10) + (colgrp << 5) + (w << 2) + (c & 3);
    half8_t va, vb;
    #pragma unroll
    for (int j = 0; j < 8; ++j) {
      float w32 = W0[(size_t)(k8 * 8 + j) * 4096 + gcol] * 32.0f;
      _Float16 p1 = (_Float16)w32;
      float r = w32 - (float)p1;
      va[j] = p1; vb[j] = (_Float16)(r * 2048.0f);
    }
    *(half8_t*)&W0a[(size_t)gp * 1536 + k8 * 8] = va;
    *(half8_t*)&W0b[(size_t)gp * 1536 + k8 * 8] = vb;
  } else if (gid < W0N + W1N) {
    int g2 = gid - W0N;
    int k8 = g2 >> 12, gp = g2 & 4095;
    int colgrp = gp >> 7, w = (gp >> 4) & 7, c = gp & 15;
    int gcol = ((c >> 2) << 10) + (colgrp << 5) + (w << 2) + (c & 3);
    half8_t va, vb;
    #pragma unroll
    for (int j = 0; j < 8; ++j) {
      float w32 = W1[(size_t)(k8 * 8 + j) * 4096 + gcol] * 32.0f;
      _Float16 p1 = (_Float16)w32;
      float r = w32 - (float)p1;
      va[j] = p1; vb[j] = (_Float16)(r * 2048.0f);
    }
    *(half8_t*)&W1a[(size_t)gp * 2048 + k8 * 8] = va;
    *(half8_t*)&W1b[(size_t)gp * 2048 + k8 * 8] = vb;
  } else if (gid < W0N + W1N + 6 * 4096) {
    int g2 = gid - W0N - W1N;
    int j = g2 >> 12, gp = g2 & 4095;
    int colgrp = gp >> 7, w = (gp >> 4) & 7, c = gp & 15;
    int gcol = ((c >> 2) << 10) + (colgrp << 5) + (w << 2) + (c & 3);
    const float* src = (j == 0) ? b0 : (j == 1) ? g0 : (j == 2) ? be0
                     : (j == 3) ? b1 : (j == 4) ? g1 : be1;
    vecs[j * 4096 + gp] = src[gcol];
  }
}

#define MFMA16(A, B, C) __builtin_amdgcn_mfma_f32_16x16x32_f16(A, B, C, 0, 0, 0)

// ---- GROUP-LOCAL barrier: 32 arrivals (one mtile group)
__device__ __forceinline__ void groupbar(unsigned* bars, int grp, int tid, unsigned ep) {
  __syncthreads();
  if (tid == 0) {
    const int q = ep & 1;
    unsigned old = __hip_atomic_fetch_add(&bars[(grp * 2 + q) * 32], 1u,
                                          __ATOMIC_RELAXED, __HIP_MEMORY_SCOPE_AGENT);
    if (old == 31u) {
      __hip_atomic_store(&bars[(grp * 2 + q) * 32], 0u, __ATOMIC_RELAXED, __HIP_MEMORY_SCOPE_SYSTEM);
      __hip_atomic_store(&bars[1024 + grp * 32], ep, __ATOMIC_RELEASE, __HIP_MEMORY_SCOPE_SYSTEM);
    }
    while (__hip_atomic_load(&bars[1024 + grp * 32], __ATOMIC_RELAXED, __HIP_MEMORY_SCOPE_SYSTEM) < ep) {}
  }
  __syncthreads();
}

// 256 WGs x 512 thr (r14 structure, fused H1+H0). WG = (mtile = wgid>>5,
// colgrp = wgid&31); wave wid = 16-col tile. h transported PACKED (u32 =
// {p1,p2} fp16 pair): 16B sc0sc1 asm loads for the stage, single 4B stores.
__global__ void __launch_bounds__(512, 2) lstm_seq(
    const float* __restrict__ x,
    const _Float16* __restrict__ W0ap,
    const _Float16* __restrict__ W0bp,
    const _Float16* __restrict__ W1ap,
    const _Float16* __restrict__ W1bp,
    const float* __restrict__ vecs,
    unsigned* __restrict__ hpk,
    float* __restrict__ stats,
    unsigned* __restrict__ bars,
    const float* __restrict__ fcW,
    const float* __restrict__ fcb,
    float* __restrict__ out)
{
  extern __shared__ _Float16 hS[];    // [2 planes][16 rows][SH]
  const int tid = threadIdx.x;
  const int wgid = blockIdx.x;
  const int mtile = wgid >> 5;         // 0..7 = group
  const int colgrp = wgid & 31;        // 0..31 (128-col group)
  const int wid = tid >> 6;            // 0..7 = 16-col tile
  const int lane = tid & 63;
  const int c16 = lane & 15;
  const int klo = lane >> 4;
  const int rowbase = mtile * 16;

  const int gp = colgrp * 128 + wid * 16 + c16;
  const float b0v  = vecs[gp];
  const float g0v  = vecs[4096 + gp];
  const float be0v = vecs[8192 + gp];
  const float b1v  = vecs[12288 + gp];
  const float g1v  = vecs[16384 + gp];
  const float be1v = vecs[20480 + gp];

  const int arow = rowbase + c16;
  const float* xbase = x + (size_t)arow * 512 * 512; // x[row][t][d]
  const _Float16* w0a = W0ap + (size_t)gp * 1536;
  const _Float16* w0b = W0bp + (size_t)gp * 1536;
  const _Float16* w1a = W1ap + (size_t)gp * 2048;
  const _Float16* w1b = W1bp + (size_t)gp * 2048;
  const int repbase = (colgrp & 15) << 2;            // rep*4 for stats writes
  const int cbase = colgrp * 32 + wid * 4;           // h-unit base for this wave

  float c0s[4] = {0,0,0,0};
  float c1s[4] = {0,0,0,0};
  unsigned ep = 0;
  u32x4_t stg[16];                    // in-flight stage registers (packed)

// chunk decode: 16 rows x 512 chunks/row (chunk = 4 packed cols = 16B)
#define HDECODE(Q)                                                            \
      int idx = tid + 512 * (Q);                                              \
      int row = idx >> 9;                                                     \
      int ck4 = idx & 511;

// issue this WG's full h stage (16 rows x 2048 packed cols) — 16B asm loads
#define STAGE_ISSUE() {                                                       \
    _Pragma("unroll")                                                         \
    for (int q = 0; q < 16; ++q) {                                            \
      HDECODE(q)                                                              \
      stg[q] = ld_u32x4_sys(&hpk[(size_t)(rowbase + row) * 2048 + ck4 * 4]);  \
    } }

// drain + unpack to the two LDS planes + sync
#define STAGE_COMMIT() {                                                      \
    asm volatile("s_waitcnt vmcnt(0)" ::: "memory");                          \
    __builtin_amdgcn_sched_barrier(0);                                        \
    _Pragma("unroll")                                                         \
    for (int q = 0; q < 16; ++q) {                                            \
      HDECODE(q)                                                              \
      unsigned w0 = stg[q][0], w1 = stg[q][1], w2 = stg[q][2], w3 = stg[q][3];\
      unsigned lo01 = (w0 & 0xFFFFu) | (w1 << 16);                            \
      unsigned lo23 = (w2 & 0xFFFFu) | (w3 << 16);                            \
      unsigned hi01 = (w0 >> 16) | (w1 & 0xFFFF0000u);                        \
      unsigned hi23 = (w2 >> 16) | (w3 & 0xFFFF0000u);                        \
      unsigned* d1 = (unsigned*)&hS[row * SH + ck4 * 4];                      \
      d1[0] = lo01; d1[1] = lo23;                                             \
      unsigned* d2 = (unsigned*)&hS[HMOFF + row * SH + ck4 * 4];              \
      d2[0] = hi01; d2[1] = hi23;                                             \
    }                                                                         \
    __syncthreads(); }

#define SPLIT2(E, J) { float e_ = (E); _Float16 h1_ = (_Float16)e_;           \
  float r_ = e_ - (float)h1_; ah[J] = h1_; am[J] = (_Float16)(r_ * 2048.0f); }

#define PROD3(HA, MA) \
  HA = MFMA16(ah, bh0, HA);                                                   \
  MA = MFMA16(ah, bm0, MA);                                                   \
  MA = MFMA16(am, bh0, MA);

#define X_BODY(KB, HA, MA) {                                                  \
      float4 xu = *(const float4*)(xp + (KB) * 32);                           \
      float4 xw = *(const float4*)(xp + (KB) * 32 + 4);                       \
      half8_t ah, am;                                                         \
      SPLIT2(xu.x, 0) SPLIT2(xu.y, 1) SPLIT2(xu.z, 2) SPLIT2(xu.w, 3)         \
      SPLIT2(xw.x, 4) SPLIT2(xw.y, 5) SPLIT2(xw.z, 6) SPLIT2(xw.w, 7)         \
      half8_t bh0 = *(const half8_t*)&w0a[(KB) * 32 + klo * 8];               \
      half8_t bm0 = *(const half8_t*)&w0b[(KB) * 32 + klo * 8];               \
      PROD3(HA, MA) }

#define H0_BODY(KB, HA, MA) {                                                 \
      half8_t ah = *(const half8_t*)&hS[c16 * SH + (KB) * 32 + klo * 8];      \
      half8_t am = *(const half8_t*)&hS[HMOFF + c16 * SH + (KB) * 32 + klo * 8]; \
      half8_t bh0 = *(const half8_t*)&w0a[512 + (KB) * 32 + klo * 8];         \
      half8_t bm0 = *(const half8_t*)&w0b[512 + (KB) * 32 + klo * 8];         \
      PROD3(HA, MA) }

#define H1_BODY(KB, HA, MA) {                                                 \
      half8_t ah = *(const half8_t*)&hS[c16 * SH + (KB) * 32 + klo * 8];      \
      half8_t am = *(const half8_t*)&hS[HMOFF + c16 * SH + (KB) * 32 + klo * 8]; \
      half8_t bh0 = *(const half8_t*)&w1a[(KB) * 32 + klo * 8];               \
      half8_t bm0 = *(const half8_t*)&w1b[(KB) * 32 + klo * 8];               \
      PROD3(HA, MA) }

#define STAT_ADD(V, BUF) {                                                    \
    _Pragma("unroll")                                                         \
    for (int r = 0; r < 4; ++r) {                                             \
      float s = V[r];                                                         \
      float q = V[r]*V[r];                                                    \
      _Pragma("unroll")                                                       \
      for (int m = 1; m <= 8; m <<= 1) { s += __shfl_xor(s, m); q += __shfl_xor(q, m); } \
      if (c16 == 0) {                                                         \
        int row = rowbase + klo * 4 + r;                                      \
        atomicAdd(&stats[(repbase + (BUF)) * 256 + row * 2 + 0], s);          \
        atomicAdd(&stats[(repbase + (BUF)) * 256 + row * 2 + 1], q);          \
      }                                                                       \
    } }

// LN + LSTM cell; h written as ONE packed 4B SYSTEM store per unit.
#define CELL(V, BUF, CS, GC, BEC, HB) {                                       \
    _Pragma("unroll")                                                         \
    for (int r = 0; r < 4; ++r) {                                             \
      int row = rowbase + klo * 4 + r;                                        \
      const float* sp = stats + ((c16 << 2) + (BUF)) * 256 + row * 2;         \
      float s_ = ld_f_coh(sp), q_ = ld_f_coh(sp + 1);                         \
      _Pragma("unroll")                                                       \
      for (int m = 1; m <= 8; m <<= 1) { s_ += __shfl_xor(s_, m); q_ += __shfl_xor(q_, m); } \
      float mean = s_ * (1.0f / 4096.0f);                                     \
      float msq  = q_ * (1.0f / 4096.0f);                                     \
      float rstd = rsqrtf(msq - mean * mean + 1e-5f);                         \
      float gh = (V[r] - mean) * rstd * GC + BEC;                             \
      float fg = __shfl_down(gh, 4);                                          \
      float gg = __shfl_down(gh, 8);                                          \
      float og = __shfl_down(gh, 12);                                         \
      if (c16 < 4) {                                                          \
        float iv = sigm(gh), fv = sigm(fg), zv = tanh_fast(gg), ov = sigm(og); \
        float cc = fv * CS[r] + iv * zv;                                      \
        CS[r] = cc;                                                           \
        float hv = ov * tanh_fast(cc);                                        \
        _Float16 h1v = (_Float16)hv;                                          \
        _Float16 h2v = (_Float16)((hv - (float)h1v) * 2048.0f);               \
        unsigned pk = (unsigned)__builtin_bit_cast(unsigned short, h1v)       \
                    | ((unsigned)__builtin_bit_cast(unsigned short, h2v) << 16); \
        __hip_atomic_store(&hpk[(size_t)row * 2048 + (HB) + cbase + c16], pk, \
                           __ATOMIC_RELAXED, __HIP_MEMORY_SCOPE_SYSTEM);      \
      }                                                                       \
    } }

  f32x4_t ahe, aho, ame, amo;     // layer-0 accumulators
  f32x4_t dhe, dho, dme, dmo;     // layer-1 accumulators
  f32x4_t a0, d0;

#define A0_X(TT) {                                                            \
    ahe = {0,0,0,0}; aho = {0,0,0,0}; ame = {0,0,0,0}; amo = {0,0,0,0};       \
    const float* xp = xbase + (size_t)(TT) * 512 + klo * 8;                   \
    _Pragma("unroll 2")                                                       \
    for (int kb = 0; kb < 16; kb += 2) {                                      \
      X_BODY(kb,     ahe, ame);                                               \
      X_BODY(kb + 1, aho, amo);                                               \
    } }

#define A0_COMBINE() {                                                        \
    a0 = (ahe + aho) * 0.03125f + (ame + amo) * (1.0f / 65536.0f);            \
    _Pragma("unroll")                                                         \
    for (int r_ = 0; r_ < 4; ++r_) a0[r_] += b0v; }

  // ---------------- prologue: A0[0] (h is zeroed) ----------------
  STAGE_ISSUE();
  STAGE_COMMIT();
  A0_X(0);
  #pragma unroll 2
  for (int kb = 0; kb < 32; kb += 2) {
    H0_BODY(kb,     ahe, ame);
    H0_BODY(kb + 1, aho, amo);
  }
  A0_COMBINE();
  STAT_ADD(a0, 0);
  groupbar(bars, mtile, tid, ++ep);
  CELL(a0, 0, c0s, g0v, be0v, 0);
  groupbar(bars, mtile, tid, ++ep);

  // ---------------- main loop ----------------
  for (int t = 0; t < 512; ++t) {
    const int par = t & 1;
    const int npar = 1 - par;

    // ===== alpha[t]: stage {h0[t], h1[t-1]}; A0_X issued between =====
    STAGE_ISSUE();                 // 16x 16B sc0sc1 loads in flight
    if (t < 511) {
      A0_X(t + 1);                 // h-independent X-part
    }
    STAGE_COMMIT();                // vmcnt(0) + unpack -> LDS + sync

    dhe = {0,0,0,0}; dho = {0,0,0,0}; dme = {0,0,0,0}; dmo = {0,0,0,0};
    if (t < 511) {
      // fused H1 + A0_H0 (2 independent weight streams; r14 chain order)
      #pragma unroll 2
      for (int i = 0; i < 32; i += 2) {
        H1_BODY(2*i,     dhe, dme);
        H1_BODY(2*i+1,   dho, dmo);
        H0_BODY(i,       ahe, ame);
        H1_BODY(2*i+2,   dhe, dme);
        H1_BODY(2*i+3,   dho, dmo);
        H0_BODY(i+1,     aho, amo);
      }
    } else {
      #pragma unroll 2
      for (int kb = 0; kb < 64; kb += 2) {
        H1_BODY(kb,     dhe, dme);
        H1_BODY(kb + 1, dho, dmo);
      }
    }
    d0 = (dhe + dho) * 0.03125f + (dme + dmo) * (1.0f / 65536.0f);
    #pragma unroll
    for (int r = 0; r < 4; ++r) d0[r] += b1v;
    STAT_ADD(d0, 2 + par);

    if (t < 511) {
      A0_COMBINE();
      STAT_ADD(a0, npar);
    }

    // group-local stats zeroing
    if (colgrp < 16 && tid < 64) {
      int bufsel = ((tid >> 5) == 0) ? (2 + npar) : par;
      st_f_coh(&stats[((colgrp << 2) + bufsel) * 256 + mtile * 32 + (tid & 31)], 0.0f);
    }

    groupbar(bars, mtile, tid, ++ep);

    // ===== beta[t]: B1[t] (+ B0[t+1]) =====
    CELL(d0, 2 + par, c1s, g1v, be1v, 1024);
    if (t < 511) {
      CELL(a0, npar, c0s, g0v, be0v, 0);
    }
    groupbar(bars, mtile, tid, ++ep);
  }

  // ---------------- final fc (group-local): rows of this mtile ----------
  {
    if (tid < 256) {
      int b = rowbase + (tid >> 4);
      int o = colgrp * 16 + (tid & 15);
      const unsigned* p = hpk + (size_t)b * 2048 + 1024;
      float s = fcb[o];
      #pragma unroll 4
      for (int k = 0; k < 1024; k += 2) {
        u64 v = __hip_atomic_load((u64*)(p + k), __ATOMIC_RELAXED, __HIP_MEMORY_SCOPE_SYSTEM);
        unsigned wa = (unsigned)v, wb = (unsigned)(v >> 32);
        float h0v = (float)__builtin_bit_cast(_Float16, (unsigned short)(wa & 0xFFFFu))
                  + (float)__builtin_bit_cast(_Float16, (unsigned short)(wa >> 16)) * (1.0f / 2048.0f);
        float h1v = (float)__builtin_bit_cast(_Float16, (unsigned short)(wb & 0xFFFFu))
                  + (float)__builtin_bit_cast(_Float16, (unsigned short)(wb >> 16)) * (1.0f / 2048.0f);
        s = fmaf(h0v, fcW[k * 512 + o], s);
        s = fmaf(h1v, fcW[(k + 1) * 512 + o], s);
      }
      out[b * 512 + o] = s;
    }
  }
}

extern "C" void kernel_launch(void* const* d_in, const int* in_sizes, int n_in,
                              void* d_out, int out_size, void* d_ws, size_t ws_size,
                              hipStream_t stream) {
  const float* x   = (const float*)d_in[0];
  const float* W0  = (const float*)d_in[1];
  const float* b0  = (const float*)d_in[2];
  const float* g0  = (const float*)d_in[3];
  const float* be0 = (const float*)d_in[4];
  const float* W1  = (const float*)d_in[5];
  const float* b1  = (const float*)d_in[6];
  const float* g1  = (const float*)d_in[7];
  const float* be1 = (const float*)d_in[8];
  const float* fcW = (const float*)d_in[9];
  const float* fcb = (const float*)d_in[10];
  float* out = (float*)d_out;

  char* ws = (char*)d_ws;
  _Float16* W0a  = (_Float16*)(ws);
  _Float16* W0b  = (_Float16*)(ws + 12582912);
  _Float16* W1a  = (_Float16*)(ws + 25165824);
  _Float16* W1b  = (_Float16*)(ws + 41943040);
  float* vecs    = (float*)(ws + 58720256);
  unsigned* hpk  = (unsigned*)(ws + 58818560);
  float* stats   = (float*)(ws + 59867136);
  unsigned* bars = (unsigned*)(ws + 59932672);

  // re-zero packed h + stats + barrier state every call (graph replays reuse ws)
  hipMemsetAsync(hpk, 0, 1048576 + 65536 + 8192, stream);
  lstm_prep<<<7264, 256, 0, stream>>>(W0, W1, b0, g0, be0, b1, g1, be1,
                                      W0a, W0b, W1a, W1b, vecs);

  hipFuncSetAttribute((const void*)lstm_seq,
                      hipFuncAttributeMaxDynamicSharedMemorySize, LDS_BYTES);
  void* args[] = { (void*)&x, (void*)&W0a, (void*)&W0b, (void*)&W1a, (void*)&W1b,
                   (void*)&vecs, (void*)&hpk,
                   (void*)&stats, (void*)&bars,
                   (void*)&fcW, (void*)&fcb, (void*)&out };
  hipError_t lerr = hipLaunchCooperativeKernel((const void*)lstm_seq,
                                               dim3(256), dim3(512),
                                               args, LDS_BYTES, stream);
  if (lerr != hipSuccess) {
    // coop validator rejected (>64KB-LDS occupancy calc). Grid=256 = #CUs at
    // 1 WG/CU -> co-residency capacity-guaranteed; plain launch + own barrier.
    (void)hipGetLastError();
    lstm_seq<<<dim3(256), dim3(512), LDS_BYTES, stream>>>(
        x, W0a, W0b, W1a, W1b, vecs, hpk, stats, bars, fcW, fcb, out);
  }
}

// Round 19
// 34553.104 us; speedup vs baseline: 1.2961x; 1.0271x over previous
//
#include <hip/hip_runtime.h>
#include <hip/hip_bf16.h>

typedef __attribute__((ext_vector_type(8))) _Float16 half8_t;
typedef __attribute__((ext_vector_type(4))) float f32x4_t;
typedef __attribute__((ext_vector_type(4))) unsigned u32x4_t;
typedef unsigned long long u64;

#define SH 2056                       // LDS h row stride (elems): 2048 + 8
#define HMOFF (16 * SH)               // plane-2 offset (elems)
#define LDS_BYTES (2 * 16 * SH * 2)   // 131,584 B -> 1 WG/CU, 8 waves = 2/SIMD

__device__ __forceinline__ float sigm(float z) { return 1.0f / (1.0f + __expf(-z)); }
__device__ __forceinline__ float tanh_fast(float z) {
  float e = __expf(2.0f * z);
  return 1.0f - 2.0f / (e + 1.0f);
}

// ---- coherent helpers (SYSTEM scope, compiler-tracked)
__device__ __forceinline__ float ld_f_coh(const float* p) {
  return __hip_atomic_load((float*)p, __ATOMIC_RELAXED, __HIP_MEMORY_SCOPE_SYSTEM);
}
__device__ __forceinline__ void st_f_coh(float* p, float v) {
  __hip_atomic_store(p, v, __ATOMIC_RELAXED, __HIP_MEMORY_SCOPE_SYSTEM);
}

// ---- WIDE coherent load: 16B, bypass L1+L2 (sc0 sc1); needs explicit waitcnt
__device__ __forceinline__ u32x4_t ld_u32x4_sys(const unsigned* p) {
  u32x4_t r;
  asm volatile("global_load_dwordx4 %0, %1, off sc0 sc1"
               : "=v"(r) : "v"(p) : "memory");
  return r;
}

// ws layout (bytes) — total 59,940,864 (r10..r18 known-good):
//   W0a  @ 0         : 12582912   (fp16 plane1 = fp16(32*w), [gp][k])
//   W0b  @ 12582912  : 12582912
//   W1a  @ 25165824  : 16777216
//   W1b  @ 41943040  : 16777216
//   vecs @ 58720256  : 98304
//   hpk  @ 58818560  : 1048576    (h PACKED u32 [row][2048]: lo16=p1, hi16=p2*2048)
//   stats@ 59867136  : 65536      (16 reps x 4 bufs x 256 f32)
//   bars @ 59932672  : 8192

// permutation (128-col WG groups): gp = colgrp*128 + w*16 + c,
//   gate = c>>2, uo = c&3 ; gcol = gate*1024 + colgrp*32 + w*4 + uo
__global__ void lstm_prep(const float* __restrict__ W0, const float* __restrict__ W1,
                          const float* __restrict__ b0, const float* __restrict__ g0,
                          const float* __restrict__ be0, const float* __restrict__ b1,
                          const float* __restrict__ g1, const float* __restrict__ be1,
                          _Float16* __restrict__ W0a, _Float16* __restrict__ W0b,
                          _Float16* __restrict__ W1a, _Float16* __restrict__ W1b,
                          float* __restrict__ vecs)
{
  int gid = blockIdx.x * 256 + threadIdx.x;
  const int W0N = 192 * 4096;
  const int W1N = 256 * 4096;
  if (gid < W0N) {
    int k8 = gid >> 12, gp = gid & 4095;
    int colgrp = gp >> 7, w = (gp >> 4) & 7, c = gp & 15;
    int gcol = ((c >> 2) << 10) + (colgrp << 5) + (w << 2) + (c & 3);
    half8_t va, vb;
    #pragma unroll
    for (int j = 0; j < 8; ++j) {
      float w32 = W0[(size_t)(k8 * 8 + j) * 4096 + gcol] * 32.0f;
      _Float16 p1 = (_Float16)w32;
      float r = w32 - (float)p1;
      va[j] = p1; vb[j] = (_Float16)(r * 2048.0f);
    }
    *(half8_t*)&W0a[(size_t)gp * 1536 + k8 * 8] = va;
    *(half8_t*)&W0b[(size_t)gp * 1536 + k8 * 8] = vb;
  } else if (gid < W0N + W1N) {
    int g2 = gid - W0N;
    int k8 = g2 >> 12, gp = g2 & 4095;
    int colgrp = gp >> 7, w = (gp >> 4) & 7, c = gp & 15;
    int gcol = ((c >> 2) << 10) + (colgrp << 5) + (w << 2) + (c & 3);
    half8_t va, vb;
    #pragma unroll
    for (int j = 0; j < 8; ++j) {
      float w32 = W1[(size_t)(k8 * 8 + j) * 4096 + gcol] * 32.0f;
      _Float16 p1 = (_Float16)w32;
      float r = w32 - (float)p1;
      va[j] = p1; vb[j] = (_Float16)(r * 2048.0f);
    }
    *(half8_t*)&W1a[(size_t)gp * 2048 + k8 * 8] = va;
    *(half8_t*)&W1b[(size_t)gp * 2048 + k8 * 8] = vb;
  } else if (gid < W0N + W1N + 6 * 4096) {
    int g2 = gid - W0N - W1N;
    int j = g2 >> 12, gp = g2 & 4095;
    int colgrp = gp >> 7, w = (gp >> 4) & 7, c = gp & 15;
    int gcol = ((c >> 2) << 10) + (colgrp << 5) + (w << 2) + (c & 3);
    const float* src = (j == 0) ? b0 : (j == 1) ? g0 : (j == 2) ? be0
                     : (j == 3) ? b1 : (j == 4) ? g1 : be1;
    vecs[j * 4096 + gp] = src[gcol];
  }
}

#define MFMA16(A, B, C) __builtin_amdgcn_mfma_f32_16x16x32_f16(A, B, C, 0, 0, 0)

// ---- GROUP-LOCAL barrier: 32 arrivals (one mtile group)
__device__ __forceinline__ void groupbar(unsigned* bars, int grp, int tid, unsigned ep) {
  __syncthreads();
  if (tid == 0) {
    const int q = ep & 1;
    unsigned old = __hip_atomic_fetch_add(&bars[(grp * 2 + q) * 32], 1u,
                                          __ATOMIC_RELAXED, __HIP_MEMORY_SCOPE_AGENT);
    if (old == 31u) {
      __hip_atomic_store(&bars[(grp * 2 + q) * 32], 0u, __ATOMIC_RELAXED, __HIP_MEMORY_SCOPE_SYSTEM);
      __hip_atomic_store(&bars[1024 + grp * 32], ep, __ATOMIC_RELEASE, __HIP_MEMORY_SCOPE_SYSTEM);
    }
    while (__hip_atomic_load(&bars[1024 + grp * 32], __ATOMIC_RELAXED, __HIP_MEMORY_SCOPE_SYSTEM) < ep) {}
  }
  __syncthreads();
}

// 256 WGs x 512 thr (r18 structure). WG = (mtile = wgid>>5, colgrp = wgid&31);
// wave wid = 16-col tile. Packed h transport (u32/unit). NEW: LN stats gathered
// cooperatively through LDS (512 SYSTEM loads/WG instead of 8192; CELL reads
// mean/var from LDS, no shuffle chain).
__global__ void __launch_bounds__(512, 2) lstm_seq(
    const float* __restrict__ x,
    const _Float16* __restrict__ W0ap,
    const _Float16* __restrict__ W0bp,
    const _Float16* __restrict__ W1ap,
    const _Float16* __restrict__ W1bp,
    const float* __restrict__ vecs,
    unsigned* __restrict__ hpk,
    float* __restrict__ stats,
    unsigned* __restrict__ bars,
    const float* __restrict__ fcW,
    const float* __restrict__ fcb,
    float* __restrict__ out)
{
  extern __shared__ _Float16 hS[];    // [2 planes][16 rows][SH]
  __shared__ float sred[2][32];       // [0]=L1 buf, [1]=L0 buf; ent = rr*2+{s,q}
  const int tid = threadIdx.x;
  const int wgid = blockIdx.x;
  const int mtile = wgid >> 5;         // 0..7 = group
  const int colgrp = wgid & 31;        // 0..31 (128-col group)
  const int wid = tid >> 6;            // 0..7 = 16-col tile
  const int lane = tid & 63;
  const int c16 = lane & 15;
  const int klo = lane >> 4;
  const int rowbase = mtile * 16;

  const int gp = colgrp * 128 + wid * 16 + c16;
  const float b0v  = vecs[gp];
  const float g0v  = vecs[4096 + gp];
  const float be0v = vecs[8192 + gp];
  const float b1v  = vecs[12288 + gp];
  const float g1v  = vecs[16384 + gp];
  const float be1v = vecs[20480 + gp];

  const int arow = rowbase + c16;
  const float* xbase = x + (size_t)arow * 512 * 512; // x[row][t][d]
  const _Float16* w0a = W0ap + (size_t)gp * 1536;
  const _Float16* w0b = W0bp + (size_t)gp * 1536;
  const _Float16* w1a = W1ap + (size_t)gp * 2048;
  const _Float16* w1b = W1bp + (size_t)gp * 2048;
  const int repbase = (colgrp & 15) << 2;            // rep*4 for stats writes
  const int cbase = colgrp * 32 + wid * 4;           // h-unit base for this wave

  float c0s[4] = {0,0,0,0};
  float c1s[4] = {0,0,0,0};
  unsigned ep = 0;
  u32x4_t stg[16];                    // in-flight stage registers (packed)

// chunk decode: 16 rows x 512 chunks/row (chunk = 4 packed cols = 16B)
#define HDECODE(Q)                                                            \
      int idx = tid + 512 * (Q);                                              \
      int row = idx >> 9;                                                     \
      int ck4 = idx & 511;

#define STAGE_ISSUE() {                                                       \
    _Pragma("unroll")                                                         \
    for (int q = 0; q < 16; ++q) {                                            \
      HDECODE(q)                                                              \
      stg[q] = ld_u32x4_sys(&hpk[(size_t)(rowbase + row) * 2048 + ck4 * 4]);  \
    } }

#define STAGE_COMMIT() {                                                      \
    asm volatile("s_waitcnt vmcnt(0)" ::: "memory");                          \
    __builtin_amdgcn_sched_barrier(0);                                        \
    _Pragma("unroll")                                                         \
    for (int q = 0; q < 16; ++q) {                                            \
      HDECODE(q)                                                              \
      unsigned w0 = stg[q][0], w1 = stg[q][1], w2 = stg[q][2], w3 = stg[q][3];\
      unsigned lo01 = (w0 & 0xFFFFu) | (w1 << 16);                            \
      unsigned lo23 = (w2 & 0xFFFFu) | (w3 << 16);                            \
      unsigned hi01 = (w0 >> 16) | (w1 & 0xFFFF0000u);                        \
      unsigned hi23 = (w2 >> 16) | (w3 & 0xFFFF0000u);                        \
      unsigned* d1 = (unsigned*)&hS[row * SH + ck4 * 4];                      \
      d1[0] = lo01; d1[1] = lo23;                                             \
      unsigned* d2 = (unsigned*)&hS[HMOFF + row * SH + ck4 * 4];              \
      d2[0] = hi01; d2[1] = hi23;                                             \
    }                                                                         \
    __syncthreads(); }

#define SPLIT2(E, J) { float e_ = (E); _Float16 h1_ = (_Float16)e_;           \
  float r_ = e_ - (float)h1_; ah[J] = h1_; am[J] = (_Float16)(r_ * 2048.0f); }

#define PROD3(HA, MA) \
  HA = MFMA16(ah, bh0, HA);                                                   \
  MA = MFMA16(ah, bm0, MA);                                                   \
  MA = MFMA16(am, bh0, MA);

#define X_BODY(KB, HA, MA) {                                                  \
      float4 xu = *(const float4*)(xp + (KB) * 32);                           \
      float4 xw = *(const float4*)(xp + (KB) * 32 + 4);                       \
      half8_t ah, am;                                                         \
      SPLIT2(xu.x, 0) SPLIT2(xu.y, 1) SPLIT2(xu.z, 2) SPLIT2(xu.w, 3)         \
      SPLIT2(xw.x, 4) SPLIT2(xw.y, 5) SPLIT2(xw.z, 6) SPLIT2(xw.w, 7)         \
      half8_t bh0 = *(const half8_t*)&w0a[(KB) * 32 + klo * 8];               \
      half8_t bm0 = *(const half8_t*)&w0b[(KB) * 32 + klo * 8];               \
      PROD3(HA, MA) }

#define H0_BODY(KB, HA, MA) {                                                 \
      half8_t ah = *(const half8_t*)&hS[c16 * SH + (KB) * 32 + klo * 8];      \
      half8_t am = *(const half8_t*)&hS[HMOFF + c16 * SH + (KB) * 32 + klo * 8]; \
      half8_t bh0 = *(const half8_t*)&w0a[512 + (KB) * 32 + klo * 8];         \
      half8_t bm0 = *(const half8_t*)&w0b[512 + (KB) * 32 + klo * 8];         \
      PROD3(HA, MA) }

#define H1_BODY(KB, HA, MA) {                                                 \
      half8_t ah = *(const half8_t*)&hS[c16 * SH + (KB) * 32 + klo * 8];      \
      half8_t am = *(const half8_t*)&hS[HMOFF + c16 * SH + (KB) * 32 + klo * 8]; \
      half8_t bh0 = *(const half8_t*)&w1a[(KB) * 32 + klo * 8];               \
      half8_t bm0 = *(const half8_t*)&w1b[(KB) * 32 + klo * 8];               \
      PROD3(HA, MA) }

#define STAT_ADD(V, BUF) {                                                    \
    _Pragma("unroll")                                                         \
    for (int r = 0; r < 4; ++r) {                                             \
      float s = V[r];                                                         \
      float q = V[r]*V[r];                                                    \
      _Pragma("unroll")                                                       \
      for (int m = 1; m <= 8; m <<= 1) { s += __shfl_xor(s, m); q += __shfl_xor(q, m); } \
      if (c16 == 0) {                                                         \
        int row = rowbase + klo * 4 + r;                                      \
        atomicAdd(&stats[(repbase + (BUF)) * 256 + row * 2 + 0], s);          \
        atomicAdd(&stats[(repbase + (BUF)) * 256 + row * 2 + 1], q);          \
      }                                                                       \
    } }

// cooperative stats gather: thread (rep=tid>>5, ent=tid&31) reads one replica
// entry per buffer, LDS-atomicAdd into sred. Must be preceded by sred zeroing
// + a barrier, followed by __syncthreads before CELL reads.
#define STATS_GATHER(BUFD, DO_A, BUFA) {                                      \
    int rep_ = tid >> 5, ent_ = tid & 31;                                     \
    float vD_ = ld_f_coh(&stats[((rep_ << 2) + (BUFD)) * 256 + rowbase * 2 + ent_]); \
    atomicAdd(&sred[0][ent_], vD_);                                           \
    if (DO_A) {                                                               \
      float vA_ = ld_f_coh(&stats[((rep_ << 2) + (BUFA)) * 256 + rowbase * 2 + ent_]); \
      atomicAdd(&sred[1][ent_], vA_);                                         \
    }                                                                         \
    __syncthreads(); }

// LN + LSTM cell; mean/var from LDS (SIDX = 0 for L1-buf, 1 for L0-buf);
// h written as ONE packed 4B SYSTEM store per unit.
#define CELL(V, SIDX, CS, GC, BEC, HB) {                                      \
    _Pragma("unroll")                                                         \
    for (int r = 0; r < 4; ++r) {                                             \
      int rr = klo * 4 + r;                                                   \
      int row = rowbase + rr;                                                 \
      float s_ = sred[SIDX][rr * 2 + 0];                                      \
      float q_ = sred[SIDX][rr * 2 + 1];                                      \
      float mean = s_ * (1.0f / 4096.0f);                                     \
      float msq  = q_ * (1.0f / 4096.0f);                                     \
      float rstd = rsqrtf(msq - mean * mean + 1e-5f);                         \
      float gh = (V[r] - mean) * rstd * GC + BEC;                             \
      float fg = __shfl_down(gh, 4);                                          \
      float gg = __shfl_down(gh, 8);                                          \
      float og = __shfl_down(gh, 12);                                         \
      if (c16 < 4) {                                                          \
        float iv = sigm(gh), fv = sigm(fg), zv = tanh_fast(gg), ov = sigm(og); \
        float cc = fv * CS[r] + iv * zv;                                      \
        CS[r] = cc;                                                           \
        float hv = ov * tanh_fast(cc);                                        \
        _Float16 h1v = (_Float16)hv;                                          \
        _Float16 h2v = (_Float16)((hv - (float)h1v) * 2048.0f);               \
        unsigned pk = (unsigned)__builtin_bit_cast(unsigned short, h1v)       \
                    | ((unsigned)__builtin_bit_cast(unsigned short, h2v) << 16); \
        __hip_atomic_store(&hpk[(size_t)row * 2048 + (HB) + cbase + c16], pk, \
                           __ATOMIC_RELAXED, __HIP_MEMORY_SCOPE_SYSTEM);      \
      }                                                                       \
    } }

  f32x4_t ahe, aho, ame, amo;     // layer-0 accumulators
  f32x4_t dhe, dho, dme, dmo;     // layer-1 accumulators
  f32x4_t a0, d0;

#define A0_X(TT) {                                                            \
    ahe = {0,0,0,0}; aho = {0,0,0,0}; ame = {0,0,0,0}; amo = {0,0,0,0};       \
    const float* xp = xbase + (size_t)(TT) * 512 + klo * 8;                   \
    _Pragma("unroll 2")                                                       \
    for (int kb = 0; kb < 16; kb += 2) {                                      \
      X_BODY(kb,     ahe, ame);                                               \
      X_BODY(kb + 1, aho, amo);                                               \
    } }

#define A0_COMBINE() {                                                        \
    a0 = (ahe + aho) * 0.03125f + (ame + amo) * (1.0f / 65536.0f);            \
    _Pragma("unroll")                                                         \
    for (int r_ = 0; r_ < 4; ++r_) a0[r_] += b0v; }

#define SRED_ZERO() { if (tid < 64) sred[tid >> 5][tid & 31] = 0.0f; }

  // ---------------- prologue: A0[0] (h is zeroed) ----------------
  STAGE_ISSUE();
  STAGE_COMMIT();
  A0_X(0);
  #pragma unroll 2
  for (int kb = 0; kb < 32; kb += 2) {
    H0_BODY(kb,     ahe, ame);
    H0_BODY(kb + 1, aho, amo);
  }
  A0_COMBINE();
  STAT_ADD(a0, 0);
  SRED_ZERO();
  groupbar(bars, mtile, tid, ++ep);
  STATS_GATHER(0, 0, 0);          // gather L0 parity-0 into sred[0]
  CELL(a0, 0, c0s, g0v, be0v, 0);
  groupbar(bars, mtile, tid, ++ep);

  // ---------------- main loop ----------------
  for (int t = 0; t < 512; ++t) {
    const int par = t & 1;
    const int npar = 1 - par;

    // ===== alpha[t]: stage {h0[t], h1[t-1]}; A0_X issued between =====
    STAGE_ISSUE();                 // 16x 16B sc0sc1 loads in flight
    if (t < 511) {
      A0_X(t + 1);                 // h-independent X-part
    }
    STAGE_COMMIT();                // vmcnt(0) + unpack -> LDS + sync

    dhe = {0,0,0,0}; dho = {0,0,0,0}; dme = {0,0,0,0}; dmo = {0,0,0,0};
    if (t < 511) {
      // fused H1 + A0_H0 (2 independent weight streams; r14 chain order)
      #pragma unroll 2
      for (int i = 0; i < 32; i += 2) {
        H1_BODY(2*i,     dhe, dme);
        H1_BODY(2*i+1,   dho, dmo);
        H0_BODY(i,       ahe, ame);
        H1_BODY(2*i+2,   dhe, dme);
        H1_BODY(2*i+3,   dho, dmo);
        H0_BODY(i+1,     aho, amo);
      }
    } else {
      #pragma unroll 2
      for (int kb = 0; kb < 64; kb += 2) {
        H1_BODY(kb,     dhe, dme);
        H1_BODY(kb + 1, dho, dmo);
      }
    }
    d0 = (dhe + dho) * 0.03125f + (dme + dmo) * (1.0f / 65536.0f);
    #pragma unroll
    for (int r = 0; r < 4; ++r) d0[r] += b1v;
    STAT_ADD(d0, 2 + par);

    if (t < 511) {
      A0_COMBINE();
      STAT_ADD(a0, npar);
    }

    // group-local stats zeroing (buffers alpha[t+1] will accumulate)
    if (colgrp < 16 && tid < 64) {
      int bufsel = ((tid >> 5) == 0) ? (2 + npar) : par;
      st_f_coh(&stats[((colgrp << 2) + bufsel) * 256 + mtile * 32 + (tid & 31)], 0.0f);
    }
    SRED_ZERO();

    groupbar(bars, mtile, tid, ++ep);

    // ===== beta[t]: gather stats once; B1[t] (+ B0[t+1]) =====
    STATS_GATHER(2 + par, (t < 511), npar);
    CELL(d0, 0, c1s, g1v, be1v, 1024);
    if (t < 511) {
      CELL(a0, 1, c0s, g0v, be0v, 0);
    }
    groupbar(bars, mtile, tid, ++ep);
  }

  // ---------------- final fc (group-local): rows of this mtile ----------
  {
    if (tid < 256) {
      int b = rowbase + (tid >> 4);
      int o = colgrp * 16 + (tid & 15);
      const unsigned* p = hpk + (size_t)b * 2048 + 1024;
      float s = fcb[o];
      #pragma unroll 4
      for (int k = 0; k < 1024; k += 2) {
        u64 v = __hip_atomic_load((u64*)(p + k), __ATOMIC_RELAXED, __HIP_MEMORY_SCOPE_SYSTEM);
        unsigned wa = (unsigned)v, wb = (unsigned)(v >> 32);
        float h0v = (float)__builtin_bit_cast(_Float16, (unsigned short)(wa & 0xFFFFu))
                  + (float)__builtin_bit_cast(_Float16, (unsigned short)(wa >> 16)) * (1.0f / 2048.0f);
        float h1v = (float)__builtin_bit_cast(_Float16, (unsigned short)(wb & 0xFFFFu))
                  + (float)__builtin_bit_cast(_Float16, (unsigned short)(wb >> 16)) * (1.0f / 2048.0f);
        s = fmaf(h0v, fcW[k * 512 + o], s);
        s = fmaf(h1v, fcW[(k + 1) * 512 + o], s);
      }
      out[b * 512 + o] = s;
    }
  }
}

extern "C" void kernel_launch(void* const* d_in, const int* in_sizes, int n_in,
                              void* d_out, int out_size, void* d_ws, size_t ws_size,
                              hipStream_t stream) {
  const float* x   = (const float*)d_in[0];
  const float* W0  = (const float*)d_in[1];
  const float* b0  = (const float*)d_in[2];
  const float* g0  = (const float*)d_in[3];
  const float* be0 = (const float*)d_in[4];
  const float* W1  = (const float*)d_in[5];
  const float* b1  = (const float*)d_in[6];
  const float* g1  = (const float*)d_in[7];
  const float* be1 = (const float*)d_in[8];
  const float* fcW = (const float*)d_in[9];
  const float* fcb = (const float*)d_in[10];
  float* out = (float*)d_out;

  char* ws = (char*)d_ws;
  _Float16* W0a  = (_Float16*)(ws);
  _Float16* W0b  = (_Float16*)(ws + 12582912);
  _Float16* W1a  = (_Float16*)(ws + 25165824);
  _Float16* W1b  = (_Float16*)(ws + 41943040);
  float* vecs    = (float*)(ws + 58720256);
  unsigned* hpk  = (unsigned*)(ws + 58818560);
  float* stats   = (float*)(ws + 59867136);
  unsigned* bars = (unsigned*)(ws + 59932672);

  // re-zero packed h + stats + barrier state every call (graph replays reuse ws)
  hipMemsetAsync(hpk, 0, 1048576 + 65536 + 8192, stream);
  lstm_prep<<<7264, 256, 0, stream>>>(W0, W1, b0, g0, be0, b1, g1, be1,
                                      W0a, W0b, W1a, W1b, vecs);

  hipFuncSetAttribute((const void*)lstm_seq,
                      hipFuncAttributeMaxDynamicSharedMemorySize, LDS_BYTES);
  void* args[] = { (void*)&x, (void*)&W0a, (void*)&W0b, (void*)&W1a, (void*)&W1b,
                   (void*)&vecs, (void*)&hpk,
                   (void*)&stats, (void*)&bars,
                   (void*)&fcW, (void*)&fcb, (void*)&out };
  hipError_t lerr = hipLaunchCooperativeKernel((const void*)lstm_seq,
                                               dim3(256), dim3(512),
                                               args, LDS_BYTES, stream);
  if (lerr != hipSuccess) {
    // coop validator rejected (>64KB-LDS occupancy calc). Grid=256 = #CUs at
    // 1 WG/CU -> co-residency capacity-guaranteed; plain launch + own barrier.
    (void)hipGetLastError();
    lstm_seq<<<dim3(256), dim3(512), LDS_BYTES, stream>>>(
        x, W0a, W0b, W1a, W1b, vecs, hpk, stats, bars, fcW, fcb, out);
  }
}